// Round 2
// baseline (9008.920 us; speedup 1.0000x reference)
//
#include <hip/hip_runtime.h>

#define NN 100000
#define NE 300000
#define EMB 256
#define NL 5
#define BN_EPS 1e-5f

// ---------------------------------------------------------------- embed ----
__global__ __launch_bounds__(256) void k_embed(float* __restrict__ h,
    const int* __restrict__ x, const float* __restrict__ xe1,
    const float* __restrict__ xe2) {
  const int wid = threadIdx.x >> 6, lane = threadIdx.x & 63;
  const int row = blockIdx.x * 4 + wid;           // grid 25000 -> rows exact
  const int c = lane << 2;
  const int x0 = x[row * 2], x1 = x[row * 2 + 1];
  float4 a = *(const float4*)(xe1 + (size_t)x0 * EMB + c);
  float4 b = *(const float4*)(xe2 + (size_t)x1 * EMB + c);
  *(float4*)(h + (size_t)row * EMB + c) =
      make_float4(a.x + b.x, a.y + b.y, a.z + b.z, a.w + b.w);
}

// ------------------------------------------------- init agg with self-loop -
__global__ __launch_bounds__(256) void k_init_agg(float* __restrict__ agg,
    const float* __restrict__ h, const float* __restrict__ e1l,
    const float* __restrict__ e2l) {
  const int wid = threadIdx.x >> 6, lane = threadIdx.x & 63;
  const int row = blockIdx.x * 4 + wid;
  const int c = lane << 2;
  float4 hv = *(const float4*)(h + (size_t)row * EMB + c);
  float4 s1 = *(const float4*)(e1l + 4 * EMB + c);   // self-loop attr (4,0)
  float4 s2 = *(const float4*)(e2l + c);
  *(float4*)(agg + (size_t)row * EMB + c) =
      make_float4(hv.x + s1.x + s2.x, hv.y + s1.y + s2.y,
                  hv.z + s1.z + s2.z, hv.w + s1.w + s2.w);
}

// ------------------------------------------------------- edge scatter-add --
__global__ __launch_bounds__(256) void k_scatter(float* __restrict__ agg,
    const float* __restrict__ h, const int* __restrict__ ei,
    const int* __restrict__ ea, const float* __restrict__ e1l,
    const float* __restrict__ e2l) {
  const int wid = threadIdx.x >> 6, lane = threadIdx.x & 63;
  const int e = blockIdx.x * 4 + wid;              // grid 75000 -> edges exact
  const int src = ei[e], dst = ei[NE + e];
  const int a0 = ea[e * 2], a1 = ea[e * 2 + 1];
  const int c = lane << 2;
  float4 hv = *(const float4*)(h + (size_t)src * EMB + c);
  float4 v1 = *(const float4*)(e1l + (size_t)a0 * EMB + c);
  float4 v2 = *(const float4*)(e2l + (size_t)a1 * EMB + c);
  float* p = agg + (size_t)dst * EMB + c;
  unsafeAtomicAdd(p + 0, hv.x + v1.x + v2.x);
  unsafeAtomicAdd(p + 1, hv.y + v1.y + v2.y);
  unsafeAtomicAdd(p + 2, hv.z + v1.z + v2.z);
  unsafeAtomicAdd(p + 3, hv.w + v1.w + v2.w);
}

// ------------------------------------------------------------ fp32 GEMMs ---
#define BM 64
#define BNT 64
#define BK 16
#define SMEM_FLOATS (BK * (BM + 4) + BK * BNT)  // 1088 + 1024 = 2112

// C = relu(A@B + bias)
__global__ __launch_bounds__(256) void k_gemm_relu(
    const float* __restrict__ A, const float* __restrict__ B,
    const float* __restrict__ bias, float* __restrict__ C,
    int M, int K, int N) {
  __shared__ float smem[SMEM_FLOATS];
  float (*As)[BM + 4] = (float(*)[BM + 4])smem;           // transposed A tile
  float (*Bs)[BNT] = (float(*)[BNT])(smem + BK * (BM + 4));
  const int t = threadIdx.x;
  const int tx = t & 15, ty = t >> 4;
  const int m0 = blockIdx.y * BM, n0 = blockIdx.x * BNT;
  const int ar = t >> 2, ac = (t & 3) << 2;
  const int br = t >> 4, bc = (t & 15) << 2;
  const int arow = m0 + ar;
  float acc[4][4] = {};
  for (int k0 = 0; k0 < K; k0 += BK) {
    float4 av = make_float4(0.f, 0.f, 0.f, 0.f);
    if (arow < M) av = *(const float4*)(A + (size_t)arow * K + (k0 + ac));
    As[ac + 0][ar] = av.x; As[ac + 1][ar] = av.y;
    As[ac + 2][ar] = av.z; As[ac + 3][ar] = av.w;
    *(float4*)&Bs[br][bc] = *(const float4*)(B + (size_t)(k0 + br) * N + (n0 + bc));
    __syncthreads();
#pragma unroll
    for (int kk = 0; kk < BK; ++kk) {
      float4 a4 = *(const float4*)&As[kk][ty << 2];
      float4 b4 = *(const float4*)&Bs[kk][tx << 2];
      float avr[4] = {a4.x, a4.y, a4.z, a4.w};
      float bvr[4] = {b4.x, b4.y, b4.z, b4.w};
#pragma unroll
      for (int i = 0; i < 4; ++i)
#pragma unroll
        for (int j = 0; j < 4; ++j)
          acc[i][j] = fmaf(avr[i], bvr[j], acc[i][j]);
    }
    __syncthreads();
  }
  float4 bb = *(const float4*)(bias + n0 + (tx << 2));
  float bvr[4] = {bb.x, bb.y, bb.z, bb.w};
#pragma unroll
  for (int i = 0; i < 4; ++i) {
    int row = m0 + (ty << 2) + i;
    if (row < M) {
      float4 o;
      o.x = fmaxf(acc[i][0] + bvr[0], 0.f);
      o.y = fmaxf(acc[i][1] + bvr[1], 0.f);
      o.z = fmaxf(acc[i][2] + bvr[2], 0.f);
      o.w = fmaxf(acc[i][3] + bvr[3], 0.f);
      *(float4*)(C + (size_t)row * N + n0 + (tx << 2)) = o;
    }
  }
}

// C = A@B + bias, plus per-channel sum / sumsq accumulation for BatchNorm
__global__ __launch_bounds__(256) void k_gemm_stats(
    const float* __restrict__ A, const float* __restrict__ B,
    const float* __restrict__ bias, float* __restrict__ C,
    float* __restrict__ stats, int M, int K, int N) {
  __shared__ float smem[SMEM_FLOATS];
  float (*As)[BM + 4] = (float(*)[BM + 4])smem;
  float (*Bs)[BNT] = (float(*)[BNT])(smem + BK * (BM + 4));
  const int t = threadIdx.x;
  const int tx = t & 15, ty = t >> 4;
  const int m0 = blockIdx.y * BM, n0 = blockIdx.x * BNT;
  const int ar = t >> 2, ac = (t & 3) << 2;
  const int br = t >> 4, bc = (t & 15) << 2;
  const int arow = m0 + ar;
  float acc[4][4] = {};
  for (int k0 = 0; k0 < K; k0 += BK) {
    float4 av = make_float4(0.f, 0.f, 0.f, 0.f);
    if (arow < M) av = *(const float4*)(A + (size_t)arow * K + (k0 + ac));
    As[ac + 0][ar] = av.x; As[ac + 1][ar] = av.y;
    As[ac + 2][ar] = av.z; As[ac + 3][ar] = av.w;
    *(float4*)&Bs[br][bc] = *(const float4*)(B + (size_t)(k0 + br) * N + (n0 + bc));
    __syncthreads();
#pragma unroll
    for (int kk = 0; kk < BK; ++kk) {
      float4 a4 = *(const float4*)&As[kk][ty << 2];
      float4 b4 = *(const float4*)&Bs[kk][tx << 2];
      float avr[4] = {a4.x, a4.y, a4.z, a4.w};
      float bvr[4] = {b4.x, b4.y, b4.z, b4.w};
#pragma unroll
      for (int i = 0; i < 4; ++i)
#pragma unroll
        for (int j = 0; j < 4; ++j)
          acc[i][j] = fmaf(avr[i], bvr[j], acc[i][j]);
    }
    __syncthreads();
  }
  float4 bb = *(const float4*)(bias + n0 + (tx << 2));
  float bvr[4] = {bb.x, bb.y, bb.z, bb.w};
  float s[4] = {0.f, 0.f, 0.f, 0.f}, q[4] = {0.f, 0.f, 0.f, 0.f};
#pragma unroll
  for (int i = 0; i < 4; ++i) {
    int row = m0 + (ty << 2) + i;
    if (row < M) {
      float v0 = acc[i][0] + bvr[0];
      float v1 = acc[i][1] + bvr[1];
      float v2 = acc[i][2] + bvr[2];
      float v3 = acc[i][3] + bvr[3];
      *(float4*)(C + (size_t)row * N + n0 + (tx << 2)) = make_float4(v0, v1, v2, v3);
      s[0] += v0; s[1] += v1; s[2] += v2; s[3] += v3;
      q[0] += v0 * v0; q[1] += v1 * v1; q[2] += v2 * v2; q[3] += v3 * v3;
    }
  }
  // LDS column reduction (reuse smem; last __syncthreads already passed)
  float* redS = smem;            // 1024 floats
  float* redQ = smem + 1024;     // 1024 floats
#pragma unroll
  for (int j = 0; j < 4; ++j) {
    redS[ty * BNT + (tx << 2) + j] = s[j];
    redQ[ty * BNT + (tx << 2) + j] = q[j];
  }
  __syncthreads();
  if (t < BNT) {
    float ss = 0.f, qq = 0.f;
#pragma unroll
    for (int r = 0; r < 16; ++r) {
      ss += redS[r * BNT + t];
      qq += redQ[r * BNT + t];
    }
    unsafeAtomicAdd(stats + n0 + t, ss);
    unsafeAtomicAdd(stats + 256 + n0 + t, qq);
  }
}

// -------------------------------------------------------------- BN pieces --
__global__ void k_bnfin(float* __restrict__ stats, const float* __restrict__ g,
                        const float* __restrict__ b) {
  const int c = threadIdx.x;  // 256
  float mean = stats[c] * (1.0f / NN);
  float var = stats[256 + c] * (1.0f / NN) - mean * mean;
  float rstd = rsqrtf(var + BN_EPS);
  float A = g[c] * rstd;
  stats[512 + c] = A;
  stats[768 + c] = b[c] - mean * A;
}

__global__ __launch_bounds__(256) void k_bnapply(float* __restrict__ h,
    const float* __restrict__ stats, int relu) {
  const int wid = threadIdx.x >> 6, lane = threadIdx.x & 63;
  const int row = blockIdx.x * 4 + wid;
  const int c = lane << 2;
  float4 v = *(float4*)(h + (size_t)row * EMB + c);
  float4 Av = *(const float4*)(stats + 512 + c);
  float4 Bv = *(const float4*)(stats + 768 + c);
  float4 o;
  o.x = fmaf(v.x, Av.x, Bv.x);
  o.y = fmaf(v.y, Av.y, Bv.y);
  o.z = fmaf(v.z, Av.z, Bv.z);
  o.w = fmaf(v.w, Av.w, Bv.w);
  if (relu) {
    o.x = fmaxf(o.x, 0.f); o.y = fmaxf(o.y, 0.f);
    o.z = fmaxf(o.z, 0.f); o.w = fmaxf(o.w, 0.f);
  }
  *(float4*)(h + (size_t)row * EMB + c) = o;
}

// ------------------------------------------------------------------ host ---
extern "C" void kernel_launch(void* const* d_in, const int* in_sizes, int n_in,
                              void* d_out, int out_size, void* d_ws, size_t ws_size,
                              hipStream_t stream) {
  const int* x    = (const int*)d_in[0];
  const int* ei   = (const int*)d_in[1];
  const int* ea   = (const int*)d_in[2];
  const float* xe1 = (const float*)d_in[3];
  const float* xe2 = (const float*)d_in[4];
  const float* ee1 = (const float*)d_in[5];   // [L][5][EMB]
  const float* ee2 = (const float*)d_in[6];   // [L][3][EMB]
  const float* W1  = (const float*)d_in[7];   // [L][EMB][512]
  const float* b1  = (const float*)d_in[8];   // [L][512]
  const float* W2  = (const float*)d_in[9];   // [L][512][EMB]
  const float* b2  = (const float*)d_in[10];  // [L][EMB]
  const float* bng = (const float*)d_in[11];
  const float* bnb = (const float*)d_in[12];

  float* h = (float*)d_out;                               // [NN][EMB]
  char* ws = (char*)d_ws;
  float* agg = (float*)ws;                                // [NN][EMB]
  float* hid = (float*)(ws + (size_t)NN * EMB * 4);       // [NN][512]
  float* stats = (float*)(ws + (size_t)NN * EMB * 4 + (size_t)NN * 512 * 4);

  k_embed<<<NN / 4, 256, 0, stream>>>(h, x, xe1, xe2);

  for (int l = 0; l < NL; ++l) {
    const float* e1l = ee1 + (size_t)l * 5 * EMB;
    const float* e2l = ee2 + (size_t)l * 3 * EMB;
    k_init_agg<<<NN / 4, 256, 0, stream>>>(agg, h, e1l, e2l);
    k_scatter<<<NE / 4, 256, 0, stream>>>(agg, h, ei, ea, e1l, e2l);
    k_gemm_relu<<<dim3(512 / BNT, (NN + BM - 1) / BM), 256, 0, stream>>>(
        agg, W1 + (size_t)l * EMB * 512, b1 + (size_t)l * 512, hid,
        NN, EMB, 512);
    hipMemsetAsync(stats, 0, 512 * sizeof(float), stream);
    k_gemm_stats<<<dim3(EMB / BNT, (NN + BM - 1) / BM), 256, 0, stream>>>(
        hid, W2 + (size_t)l * 512 * EMB, b2 + (size_t)l * EMB, h, stats,
        NN, 512, EMB);
    k_bnfin<<<1, 256, 0, stream>>>(stats, bng + (size_t)l * EMB,
                                   bnb + (size_t)l * EMB);
    k_bnapply<<<NN / 4, 256, 0, stream>>>(h, stats, l < NL - 1 ? 1 : 0);
  }
}

// Round 3
// 4212.851 us; speedup vs baseline: 2.1384x; 2.1384x over previous
//
#include <hip/hip_runtime.h>

#define NN 100000
#define NE 300000
#define EMB 256
#define NL 5
#define BN_EPS 1e-5f

// ---------------------------------------------------------------- embed ----
__global__ __launch_bounds__(256) void k_embed(float* __restrict__ h,
    const int* __restrict__ x, const float* __restrict__ xe1,
    const float* __restrict__ xe2) {
  const int wid = threadIdx.x >> 6, lane = threadIdx.x & 63;
  const int row = blockIdx.x * 4 + wid;           // grid 25000 -> rows exact
  const int c = lane << 2;
  const int x0 = x[row * 2], x1 = x[row * 2 + 1];
  float4 a = *(const float4*)(xe1 + (size_t)x0 * EMB + c);
  float4 b = *(const float4*)(xe2 + (size_t)x1 * EMB + c);
  *(float4*)(h + (size_t)row * EMB + c) =
      make_float4(a.x + b.x, a.y + b.y, a.z + b.z, a.w + b.w);
}

// -------------------------------------------------------------- CSR build --
// deg aliases ebuf (deg dead before ebuf is written)
__global__ __launch_bounds__(256) void k_hist(int* __restrict__ deg,
    const int* __restrict__ ei) {
  int e = blockIdx.x * 256 + threadIdx.x;
  if (e < NE) atomicAdd(&deg[ei[NE + e]], 1);
}

// single block, 1024 threads: exclusive scan of deg into rowptr + cursor
__global__ __launch_bounds__(1024) void k_scan(const int* __restrict__ deg,
    int* __restrict__ rowptr, int* __restrict__ cursor) {
  __shared__ int wsum[16], woff[17];
  const int t = threadIdx.x;
  const int lane = t & 63, w = t >> 6;
  int base = 0;
  for (int start = 0; start < NN; start += 1024) {
    const int i = start + t;
    const int v0 = (i < NN) ? deg[i] : 0;
    int v = v0;
#pragma unroll
    for (int off = 1; off < 64; off <<= 1) {
      int x = __shfl_up(v, off);
      if (lane >= off) v += x;
    }
    if (lane == 63) wsum[w] = v;
    __syncthreads();
    if (t == 0) {
      int s = 0;
#pragma unroll
      for (int k = 0; k < 16; ++k) { woff[k] = s; s += wsum[k]; }
      woff[16] = s;
    }
    __syncthreads();
    if (i < NN) {
      int excl = base + woff[w] + v - v0;
      rowptr[i] = excl;
      cursor[i] = excl;
    }
    base += woff[16];
    __syncthreads();   // protect woff/wsum before next iteration's writes
  }
  if (t == 0) rowptr[NN] = base;
}

// pack src | (combo9 << 20) into CSR slots
__global__ __launch_bounds__(256) void k_bucket(int* __restrict__ ebuf,
    int* __restrict__ cursor, const int* __restrict__ ei,
    const int* __restrict__ ea) {
  int e = blockIdx.x * 256 + threadIdx.x;
  if (e >= NE) return;
  int src = ei[e], dst = ei[NE + e];
  int c9 = ea[e * 2] * 3 + ea[e * 2 + 1];          // a0,a1 in 0..2
  int pos = atomicAdd(&cursor[dst], 1);
  ebuf[pos] = src | (c9 << 20);
}

// ecomb[l][k][c]: k<9 -> e1[l][k/3]+e2[l][k%3]; k==9 -> self-loop e1[l][4]+e2[l][0]
__global__ __launch_bounds__(256) void k_ecomb(float* __restrict__ ecomb,
    const float* __restrict__ ee1, const float* __restrict__ ee2) {
  const int c = threadIdx.x;
  const int l = blockIdx.x / 10, k = blockIdx.x % 10;
  const float* e1l = ee1 + (size_t)l * 5 * EMB;
  const float* e2l = ee2 + (size_t)l * 3 * EMB;
  float v = (k < 9) ? (e1l[(k / 3) * EMB + c] + e2l[(k % 3) * EMB + c])
                    : (e1l[4 * EMB + c] + e2l[c]);
  ecomb[(size_t)blockIdx.x * EMB + c] = v;
}

// --------------------------------------------------- gather aggregation ----
// one wave per node: agg[i] = h[i] + ecomb[9] + sum_edges (h[src] + ecomb[c9])
__global__ __launch_bounds__(256) void k_gather(float* __restrict__ agg,
    const float* __restrict__ h, const int* __restrict__ rowptr,
    const int* __restrict__ ebuf, const float* __restrict__ ecomb) {
  const int wid = threadIdx.x >> 6, lane = threadIdx.x & 63;
  const int i = blockIdx.x * 4 + wid;
  const int c = lane << 2;
  float4 hv = *(const float4*)(h + (size_t)i * EMB + c);
  float4 sv = *(const float4*)(ecomb + 9 * EMB + c);
  float sx = hv.x + sv.x, sy = hv.y + sv.y, sz = hv.z + sv.z, sw = hv.w + sv.w;
  const int beg = rowptr[i], end = rowptr[i + 1];
  for (int j = beg; j < end; ++j) {
    int p = ebuf[j];
    int src = p & 0xFFFFF, c9 = p >> 20;
    float4 a = *(const float4*)(h + (size_t)src * EMB + c);
    float4 b = *(const float4*)(ecomb + (size_t)c9 * EMB + c);
    sx += a.x + b.x; sy += a.y + b.y; sz += a.z + b.z; sw += a.w + b.w;
  }
  *(float4*)(agg + (size_t)i * EMB + c) = make_float4(sx, sy, sz, sw);
}

// ------------------------------------------------------------ fp32 GEMMs ---
#define BM 64
#define BNT 64
#define BK 16
#define SMEM_FLOATS (BK * (BM + 4) + BK * BNT)  // 1088 + 1024 = 2112

// C = relu(A@B + bias)
__global__ __launch_bounds__(256) void k_gemm_relu(
    const float* __restrict__ A, const float* __restrict__ B,
    const float* __restrict__ bias, float* __restrict__ C,
    int M, int K, int N) {
  __shared__ float smem[SMEM_FLOATS];
  float (*As)[BM + 4] = (float(*)[BM + 4])smem;           // transposed A tile
  float (*Bs)[BNT] = (float(*)[BNT])(smem + BK * (BM + 4));
  const int t = threadIdx.x;
  const int tx = t & 15, ty = t >> 4;
  const int m0 = blockIdx.y * BM, n0 = blockIdx.x * BNT;
  const int ar = t >> 2, ac = (t & 3) << 2;
  const int br = t >> 4, bc = (t & 15) << 2;
  const int arow = m0 + ar;
  float acc[4][4] = {};
  for (int k0 = 0; k0 < K; k0 += BK) {
    float4 av = make_float4(0.f, 0.f, 0.f, 0.f);
    if (arow < M) av = *(const float4*)(A + (size_t)arow * K + (k0 + ac));
    As[ac + 0][ar] = av.x; As[ac + 1][ar] = av.y;
    As[ac + 2][ar] = av.z; As[ac + 3][ar] = av.w;
    *(float4*)&Bs[br][bc] = *(const float4*)(B + (size_t)(k0 + br) * N + (n0 + bc));
    __syncthreads();
#pragma unroll
    for (int kk = 0; kk < BK; ++kk) {
      float4 a4 = *(const float4*)&As[kk][ty << 2];
      float4 b4 = *(const float4*)&Bs[kk][tx << 2];
      float avr[4] = {a4.x, a4.y, a4.z, a4.w};
      float bvr[4] = {b4.x, b4.y, b4.z, b4.w};
#pragma unroll
      for (int i = 0; i < 4; ++i)
#pragma unroll
        for (int j = 0; j < 4; ++j)
          acc[i][j] = fmaf(avr[i], bvr[j], acc[i][j]);
    }
    __syncthreads();
  }
  float4 bb = *(const float4*)(bias + n0 + (tx << 2));
  float bvr[4] = {bb.x, bb.y, bb.z, bb.w};
#pragma unroll
  for (int i = 0; i < 4; ++i) {
    int row = m0 + (ty << 2) + i;
    if (row < M) {
      float4 o;
      o.x = fmaxf(acc[i][0] + bvr[0], 0.f);
      o.y = fmaxf(acc[i][1] + bvr[1], 0.f);
      o.z = fmaxf(acc[i][2] + bvr[2], 0.f);
      o.w = fmaxf(acc[i][3] + bvr[3], 0.f);
      *(float4*)(C + (size_t)row * N + n0 + (tx << 2)) = o;
    }
  }
}

// C = A@B + bias, plus per-channel sum / sumsq accumulation for BatchNorm
__global__ __launch_bounds__(256) void k_gemm_stats(
    const float* __restrict__ A, const float* __restrict__ B,
    const float* __restrict__ bias, float* __restrict__ C,
    float* __restrict__ stats, int M, int K, int N) {
  __shared__ float smem[SMEM_FLOATS];
  float (*As)[BM + 4] = (float(*)[BM + 4])smem;
  float (*Bs)[BNT] = (float(*)[BNT])(smem + BK * (BM + 4));
  const int t = threadIdx.x;
  const int tx = t & 15, ty = t >> 4;
  const int m0 = blockIdx.y * BM, n0 = blockIdx.x * BNT;
  const int ar = t >> 2, ac = (t & 3) << 2;
  const int br = t >> 4, bc = (t & 15) << 2;
  const int arow = m0 + ar;
  float acc[4][4] = {};
  for (int k0 = 0; k0 < K; k0 += BK) {
    float4 av = make_float4(0.f, 0.f, 0.f, 0.f);
    if (arow < M) av = *(const float4*)(A + (size_t)arow * K + (k0 + ac));
    As[ac + 0][ar] = av.x; As[ac + 1][ar] = av.y;
    As[ac + 2][ar] = av.z; As[ac + 3][ar] = av.w;
    *(float4*)&Bs[br][bc] = *(const float4*)(B + (size_t)(k0 + br) * N + (n0 + bc));
    __syncthreads();
#pragma unroll
    for (int kk = 0; kk < BK; ++kk) {
      float4 a4 = *(const float4*)&As[kk][ty << 2];
      float4 b4 = *(const float4*)&Bs[kk][tx << 2];
      float avr[4] = {a4.x, a4.y, a4.z, a4.w};
      float bvr[4] = {b4.x, b4.y, b4.z, b4.w};
#pragma unroll
      for (int i = 0; i < 4; ++i)
#pragma unroll
        for (int j = 0; j < 4; ++j)
          acc[i][j] = fmaf(avr[i], bvr[j], acc[i][j]);
    }
    __syncthreads();
  }
  float4 bb = *(const float4*)(bias + n0 + (tx << 2));
  float bvr[4] = {bb.x, bb.y, bb.z, bb.w};
  float s[4] = {0.f, 0.f, 0.f, 0.f}, q[4] = {0.f, 0.f, 0.f, 0.f};
#pragma unroll
  for (int i = 0; i < 4; ++i) {
    int row = m0 + (ty << 2) + i;
    if (row < M) {
      float v0 = acc[i][0] + bvr[0];
      float v1 = acc[i][1] + bvr[1];
      float v2 = acc[i][2] + bvr[2];
      float v3 = acc[i][3] + bvr[3];
      *(float4*)(C + (size_t)row * N + n0 + (tx << 2)) = make_float4(v0, v1, v2, v3);
      s[0] += v0; s[1] += v1; s[2] += v2; s[3] += v3;
      q[0] += v0 * v0; q[1] += v1 * v1; q[2] += v2 * v2; q[3] += v3 * v3;
    }
  }
  float* redS = smem;            // 1024 floats
  float* redQ = smem + 1024;     // 1024 floats
#pragma unroll
  for (int j = 0; j < 4; ++j) {
    redS[ty * BNT + (tx << 2) + j] = s[j];
    redQ[ty * BNT + (tx << 2) + j] = q[j];
  }
  __syncthreads();
  if (t < BNT) {
    float ss = 0.f, qq = 0.f;
#pragma unroll
    for (int r = 0; r < 16; ++r) {
      ss += redS[r * BNT + t];
      qq += redQ[r * BNT + t];
    }
    unsafeAtomicAdd(stats + n0 + t, ss);
    unsafeAtomicAdd(stats + 256 + n0 + t, qq);
  }
}

// -------------------------------------------------------------- BN pieces --
__global__ void k_bnfin(float* __restrict__ stats, const float* __restrict__ g,
                        const float* __restrict__ b) {
  const int c = threadIdx.x;  // 256
  float mean = stats[c] * (1.0f / NN);
  float var = stats[256 + c] * (1.0f / NN) - mean * mean;
  float rstd = rsqrtf(var + BN_EPS);
  float A = g[c] * rstd;
  stats[512 + c] = A;
  stats[768 + c] = b[c] - mean * A;
}

__global__ __launch_bounds__(256) void k_bnapply(float* __restrict__ h,
    const float* __restrict__ stats, int relu) {
  const int wid = threadIdx.x >> 6, lane = threadIdx.x & 63;
  const int row = blockIdx.x * 4 + wid;
  const int c = lane << 2;
  float4 v = *(float4*)(h + (size_t)row * EMB + c);
  float4 Av = *(const float4*)(stats + 512 + c);
  float4 Bv = *(const float4*)(stats + 768 + c);
  float4 o;
  o.x = fmaf(v.x, Av.x, Bv.x);
  o.y = fmaf(v.y, Av.y, Bv.y);
  o.z = fmaf(v.z, Av.z, Bv.z);
  o.w = fmaf(v.w, Av.w, Bv.w);
  if (relu) {
    o.x = fmaxf(o.x, 0.f); o.y = fmaxf(o.y, 0.f);
    o.z = fmaxf(o.z, 0.f); o.w = fmaxf(o.w, 0.f);
  }
  *(float4*)(h + (size_t)row * EMB + c) = o;
}

// ------------------------------------------------------------------ host ---
extern "C" void kernel_launch(void* const* d_in, const int* in_sizes, int n_in,
                              void* d_out, int out_size, void* d_ws, size_t ws_size,
                              hipStream_t stream) {
  const int* x    = (const int*)d_in[0];
  const int* ei   = (const int*)d_in[1];
  const int* ea   = (const int*)d_in[2];
  const float* xe1 = (const float*)d_in[3];
  const float* xe2 = (const float*)d_in[4];
  const float* ee1 = (const float*)d_in[5];   // [L][5][EMB]
  const float* ee2 = (const float*)d_in[6];   // [L][3][EMB]
  const float* W1  = (const float*)d_in[7];   // [L][EMB][512]
  const float* b1  = (const float*)d_in[8];   // [L][512]
  const float* W2  = (const float*)d_in[9];   // [L][512][EMB]
  const float* b2  = (const float*)d_in[10];  // [L][EMB]
  const float* bng = (const float*)d_in[11];
  const float* bnb = (const float*)d_in[12];

  float* h = (float*)d_out;                               // [NN][EMB]
  char* ws = (char*)d_ws;
  size_t off = 0;
  float* agg = (float*)(ws + off);    off += (size_t)NN * EMB * 4;   // 102.4 MB
  float* hid = (float*)(ws + off);    off += (size_t)NN * 512 * 4;   // 204.8 MB
  float* stats = (float*)(ws + off);  off += 1024 * 4;
  float* ecomb = (float*)(ws + off);  off += (size_t)NL * 10 * EMB * 4;
  int* rowptr = (int*)(ws + off);     off += (size_t)(NN + 1) * 4;
  int* cursor = (int*)(ws + off);     off += (size_t)NN * 4;
  int* ebuf   = (int*)(ws + off);     off += (size_t)NE * 4;
  int* deg = ebuf;   // alias: deg dead before ebuf written

  // ---- CSR build (edge structure identical across layers: build once) ----
  hipMemsetAsync(deg, 0, NN * sizeof(int), stream);
  k_hist<<<(NE + 255) / 256, 256, 0, stream>>>(deg, ei);
  k_scan<<<1, 1024, 0, stream>>>(deg, rowptr, cursor);
  k_bucket<<<(NE + 255) / 256, 256, 0, stream>>>(ebuf, cursor, ei, ea);
  k_ecomb<<<NL * 10, 256, 0, stream>>>(ecomb, ee1, ee2);

  k_embed<<<NN / 4, 256, 0, stream>>>(h, x, xe1, xe2);

  for (int l = 0; l < NL; ++l) {
    k_gather<<<NN / 4, 256, 0, stream>>>(agg, h, rowptr, ebuf,
                                         ecomb + (size_t)l * 10 * EMB);
    k_gemm_relu<<<dim3(512 / BNT, (NN + BM - 1) / BM), 256, 0, stream>>>(
        agg, W1 + (size_t)l * EMB * 512, b1 + (size_t)l * 512, hid,
        NN, EMB, 512);
    hipMemsetAsync(stats, 0, 512 * sizeof(float), stream);
    k_gemm_stats<<<dim3(EMB / BNT, (NN + BM - 1) / BM), 256, 0, stream>>>(
        hid, W2 + (size_t)l * 512 * EMB, b2 + (size_t)l * EMB, h, stats,
        NN, 512, EMB);
    k_bnfin<<<1, 256, 0, stream>>>(stats, bng + (size_t)l * EMB,
                                   bnb + (size_t)l * EMB);
    k_bnapply<<<NN / 4, 256, 0, stream>>>(h, stats, l < NL - 1 ? 1 : 0);
  }
}

// Round 6
// 3071.718 us; speedup vs baseline: 2.9329x; 1.3715x over previous
//
#include <hip/hip_runtime.h>

#define NN 100000
#define NNP 100096          // padded to multiple of 128
#define NE 300000
#define EMB 256
#define NL 5
#define BN_EPS 1e-5f

typedef __attribute__((ext_vector_type(8))) _Float16 half8;
typedef __attribute__((ext_vector_type(4))) float f32x4;

__device__ __forceinline__ ushort f2h(float f) {
  _Float16 h = (_Float16)f;
  return *(ushort*)&h;
}
__device__ __forceinline__ float h2f(ushort u) {
  _Float16 h = *(_Float16*)&u;
  return (float)h;
}

// XOR-swizzled LDS address (G4 recipe): row stride 128 B, bytecol 16B-aligned
__device__ __forceinline__ ushort* lds_at(ushort* base, int row, int bytecol) {
  return (ushort*)((char*)base + row * 128 + (bytecol ^ ((row & 7) << 4)));
}

// ---------------------------------------------------------------- embed ----
__global__ __launch_bounds__(256) void k_embed(ushort* __restrict__ hh,
    const int* __restrict__ x, const float* __restrict__ xe1,
    const float* __restrict__ xe2) {
  const int wid = threadIdx.x >> 6, lane = threadIdx.x & 63;
  const int row = blockIdx.x * 4 + wid;
  const int c = lane << 2;
  const int x0 = x[row * 2], x1 = x[row * 2 + 1];
  float4 a = *(const float4*)(xe1 + (size_t)x0 * EMB + c);
  float4 b = *(const float4*)(xe2 + (size_t)x1 * EMB + c);
  ushort4 o;
  o.x = f2h(a.x + b.x); o.y = f2h(a.y + b.y);
  o.z = f2h(a.z + b.z); o.w = f2h(a.w + b.w);
  *(ushort4*)(hh + (size_t)row * EMB + c) = o;
}

// -------------------------------------------------------------- CSR build --
__global__ __launch_bounds__(256) void k_hist(int* __restrict__ deg,
    const int* __restrict__ ei) {
  int e = blockIdx.x * 256 + threadIdx.x;
  if (e < NE) atomicAdd(&deg[ei[NE + e]], 1);
}

__global__ __launch_bounds__(1024) void k_scan(const int* __restrict__ deg,
    int* __restrict__ rowptr, int* __restrict__ cursor) {
  __shared__ int wsum[16], woff[17];
  const int t = threadIdx.x;
  const int lane = t & 63, w = t >> 6;
  int base = 0;
  for (int start = 0; start < NN; start += 1024) {
    const int i = start + t;
    const int v0 = (i < NN) ? deg[i] : 0;
    int v = v0;
#pragma unroll
    for (int off = 1; off < 64; off <<= 1) {
      int x = __shfl_up(v, off);
      if (lane >= off) v += x;
    }
    if (lane == 63) wsum[w] = v;
    __syncthreads();
    if (t == 0) {
      int s = 0;
#pragma unroll
      for (int k = 0; k < 16; ++k) { woff[k] = s; s += wsum[k]; }
      woff[16] = s;
    }
    __syncthreads();
    if (i < NN) {
      int excl = base + woff[w] + v - v0;
      rowptr[i] = excl;
      cursor[i] = excl;
    }
    base += woff[16];
    __syncthreads();
  }
  if (t == 0) rowptr[NN] = base;
}

__global__ __launch_bounds__(256) void k_bucket(int* __restrict__ ebuf,
    int* __restrict__ cursor, const int* __restrict__ ei,
    const int* __restrict__ ea) {
  int e = blockIdx.x * 256 + threadIdx.x;
  if (e >= NE) return;
  int src = ei[e], dst = ei[NE + e];
  int c9 = ea[e * 2] * 3 + ea[e * 2 + 1];
  int pos = atomicAdd(&cursor[dst], 1);
  ebuf[pos] = src | (c9 << 20);
}

// canonical per-node order -> bit-deterministic gather summation
__global__ __launch_bounds__(256) void k_sortseg(int* __restrict__ ebuf,
    const int* __restrict__ rowptr) {
  int i = blockIdx.x * 256 + threadIdx.x;
  if (i >= NN) return;
  const int beg = rowptr[i], end = rowptr[i + 1];
  for (int a = beg + 1; a < end; ++a) {
    int v = ebuf[a];
    int b = a - 1;
    while (b >= beg && ebuf[b] > v) { ebuf[b + 1] = ebuf[b]; --b; }
    ebuf[b + 1] = v;
  }
}

// ecomb[l][k][c]: k<9 -> e1[k/3]+e2[k%3]; k==9 -> self-loop e1[4]+e2[0]
__global__ __launch_bounds__(256) void k_ecomb(float* __restrict__ ecomb,
    const float* __restrict__ ee1, const float* __restrict__ ee2) {
  const int c = threadIdx.x;
  const int l = blockIdx.x / 10, k = blockIdx.x % 10;
  const float* e1l = ee1 + (size_t)l * 5 * EMB;
  const float* e2l = ee2 + (size_t)l * 3 * EMB;
  float v = (k < 9) ? (e1l[(k / 3) * EMB + c] + e2l[(k % 3) * EMB + c])
                    : (e1l[4 * EMB + c] + e2l[c]);
  ecomb[(size_t)blockIdx.x * EMB + c] = v;
}

// ------------------------------------------- weight transpose + fp16 cast --
// src fp32 [R][C] -> dst fp16 [C][R]
__global__ __launch_bounds__(256) void k_wt(const float* __restrict__ src,
    ushort* __restrict__ dst, int R, int C) {
  __shared__ float tile[32][33];
  const int t = threadIdx.x;
  const int tr = t >> 5, tc = t & 31;
  const int r0 = blockIdx.y * 32, c0 = blockIdx.x * 32;
#pragma unroll
  for (int i = 0; i < 4; ++i)
    tile[tr + 8 * i][tc] = src[(size_t)(r0 + tr + 8 * i) * C + c0 + tc];
  __syncthreads();
#pragma unroll
  for (int i = 0; i < 4; ++i)
    dst[(size_t)(c0 + tr + 8 * i) * R + r0 + tc] = f2h(tile[tc][tr + 8 * i]);
}

// --------------------------------------------------- gather aggregation ----
__global__ __launch_bounds__(256) void k_gather(ushort* __restrict__ aggh,
    const ushort* __restrict__ hh, const int* __restrict__ rowptr,
    const int* __restrict__ ebuf, const float* __restrict__ ecomb) {
  const int wid = threadIdx.x >> 6, lane = threadIdx.x & 63;
  const int i = blockIdx.x * 4 + wid;
  const int c = lane << 2;
  ushort4 hv = *(const ushort4*)(hh + (size_t)i * EMB + c);
  float4 sv = *(const float4*)(ecomb + 9 * EMB + c);
  float sx = h2f(hv.x) + sv.x, sy = h2f(hv.y) + sv.y;
  float sz = h2f(hv.z) + sv.z, sw = h2f(hv.w) + sv.w;
  const int beg = rowptr[i], end = rowptr[i + 1];
  for (int j = beg; j < end; ++j) {
    int p = ebuf[j];
    int src = p & 0xFFFFF, c9 = p >> 20;
    ushort4 a = *(const ushort4*)(hh + (size_t)src * EMB + c);
    float4 b = *(const float4*)(ecomb + (size_t)c9 * EMB + c);
    sx += h2f(a.x) + b.x; sy += h2f(a.y) + b.y;
    sz += h2f(a.z) + b.z; sw += h2f(a.w) + b.w;
  }
  ushort4 o;
  o.x = f2h(sx); o.y = f2h(sy); o.z = f2h(sz); o.w = f2h(sw);
  *(ushort4*)(aggh + (size_t)i * EMB + c) = o;
}

// ------------------------------------------------------- MFMA fp16 GEMMs ---
// 128x128 tile, BK=64, 4 waves (2x2), 64x64 per wave. Swapped mfma(B,A):
// lane holds row m=(lane&15), 4 consecutive cols n=(lane>>4)*4+reg.
// LDS: linear [128][64] fp16 + XOR swizzle (row&7)<<4 on byte offset,
// applied on BOTH the staging write and the fragment read.

// GEMM1: C[NNP][512] = relu(A[NNP][256] @ W1 + b1), A,C fp16, BT=W1^T fp16
__global__ __launch_bounds__(256) void k_mfma1(
    const ushort* __restrict__ A, const ushort* __restrict__ BT,
    const float* __restrict__ bias, ushort* __restrict__ C) {
  __shared__ ushort As[128][64];
  __shared__ ushort Bs[128][64];
  const int t = threadIdx.x;
  const int lane = t & 63, w = t >> 6;
  const int wr = w >> 1, wc = w & 1;
  const int m0 = blockIdx.y * 128, n0 = blockIdx.x * 128;
  const int r0 = t >> 3, kc = (t & 7) * 8;       // staging row / k-elem offset
  const int fm = lane & 15, g = lane >> 4;
  f32x4 acc[4][4];
#pragma unroll
  for (int i = 0; i < 4; ++i)
#pragma unroll
    for (int j = 0; j < 4; ++j) acc[i][j] = (f32x4){0.f, 0.f, 0.f, 0.f};

  for (int k0 = 0; k0 < 256; k0 += 64) {
    uint4 av[4], bv[4];
#pragma unroll
    for (int i = 0; i < 4; ++i) {
      av[i] = *(const uint4*)(A + (size_t)(m0 + r0 + 32 * i) * 256 + k0 + kc);
      bv[i] = *(const uint4*)(BT + (size_t)(n0 + r0 + 32 * i) * 256 + k0 + kc);
    }
    __syncthreads();
#pragma unroll
    for (int i = 0; i < 4; ++i) {
      *(uint4*)lds_at(&As[0][0], r0 + 32 * i, kc * 2) = av[i];
      *(uint4*)lds_at(&Bs[0][0], r0 + 32 * i, kc * 2) = bv[i];
    }
    __syncthreads();
#pragma unroll
    for (int kk = 0; kk < 2; ++kk) {
      half8 af[4], bf[4];
#pragma unroll
      for (int mi = 0; mi < 4; ++mi)
        af[mi] = *(const half8*)lds_at(&As[0][0], wr * 64 + mi * 16 + fm,
                                       kk * 64 + g * 16);
#pragma unroll
      for (int ni = 0; ni < 4; ++ni)
        bf[ni] = *(const half8*)lds_at(&Bs[0][0], wc * 64 + ni * 16 + fm,
                                       kk * 64 + g * 16);
#pragma unroll
      for (int mi = 0; mi < 4; ++mi)
#pragma unroll
        for (int ni = 0; ni < 4; ++ni)
          acc[mi][ni] = __builtin_amdgcn_mfma_f32_16x16x32_f16(
              bf[ni], af[mi], acc[mi][ni], 0, 0, 0);
    }
    __syncthreads();
  }
#pragma unroll
  for (int ni = 0; ni < 4; ++ni) {
    const int nb = n0 + wc * 64 + ni * 16 + g * 4;
    const float4 b4 = *(const float4*)(bias + nb);
#pragma unroll
    for (int mi = 0; mi < 4; ++mi) {
      const int row = m0 + wr * 64 + mi * 16 + fm;
      if (row < NN) {
        ushort4 o;
        o.x = f2h(fmaxf(acc[mi][ni].x + b4.x, 0.f));
        o.y = f2h(fmaxf(acc[mi][ni].y + b4.y, 0.f));
        o.z = f2h(fmaxf(acc[mi][ni].z + b4.z, 0.f));
        o.w = f2h(fmaxf(acc[mi][ni].w + b4.w, 0.f));
        *(ushort4*)(C + (size_t)row * 512 + nb) = o;
      }
    }
  }
}

// GEMM2: h2f[NNP][256] = A[NNP][512] @ W2 + b2 (fp32 out) + BN partials
__global__ __launch_bounds__(256) void k_mfma2(
    const ushort* __restrict__ A, const ushort* __restrict__ BT,
    const float* __restrict__ bias, float* __restrict__ h2f,
    float* __restrict__ part_s, float* __restrict__ part_q) {
  __shared__ ushort As[128][64];
  __shared__ ushort Bs[128][64];
  __shared__ float sS[128], sQ[128];
  const int t = threadIdx.x;
  if (t < 128) { sS[t] = 0.f; sQ[t] = 0.f; }
  const int lane = t & 63, w = t >> 6;
  const int wr = w >> 1, wc = w & 1;
  const int m0 = blockIdx.y * 128, n0 = blockIdx.x * 128;
  const int r0 = t >> 3, kc = (t & 7) * 8;
  const int fm = lane & 15, g = lane >> 4;
  f32x4 acc[4][4];
#pragma unroll
  for (int i = 0; i < 4; ++i)
#pragma unroll
    for (int j = 0; j < 4; ++j) acc[i][j] = (f32x4){0.f, 0.f, 0.f, 0.f};

  for (int k0 = 0; k0 < 512; k0 += 64) {
    uint4 av[4], bv[4];
#pragma unroll
    for (int i = 0; i < 4; ++i) {
      av[i] = *(const uint4*)(A + (size_t)(m0 + r0 + 32 * i) * 512 + k0 + kc);
      bv[i] = *(const uint4*)(BT + (size_t)(n0 + r0 + 32 * i) * 512 + k0 + kc);
    }
    __syncthreads();
#pragma unroll
    for (int i = 0; i < 4; ++i) {
      *(uint4*)lds_at(&As[0][0], r0 + 32 * i, kc * 2) = av[i];
      *(uint4*)lds_at(&Bs[0][0], r0 + 32 * i, kc * 2) = bv[i];
    }
    __syncthreads();
#pragma unroll
    for (int kk = 0; kk < 2; ++kk) {
      half8 af[4], bf[4];
#pragma unroll
      for (int mi = 0; mi < 4; ++mi)
        af[mi] = *(const half8*)lds_at(&As[0][0], wr * 64 + mi * 16 + fm,
                                       kk * 64 + g * 16);
#pragma unroll
      for (int ni = 0; ni < 4; ++ni)
        bf[ni] = *(const half8*)lds_at(&Bs[0][0], wc * 64 + ni * 16 + fm,
                                       kk * 64 + g * 16);
#pragma unroll
      for (int mi = 0; mi < 4; ++mi)
#pragma unroll
        for (int ni = 0; ni < 4; ++ni)
          acc[mi][ni] = __builtin_amdgcn_mfma_f32_16x16x32_f16(
              bf[ni], af[mi], acc[mi][ni], 0, 0, 0);
    }
    __syncthreads();
  }
#pragma unroll
  for (int ni = 0; ni < 4; ++ni) {
    const int nb = n0 + wc * 64 + ni * 16 + g * 4;
    const float4 b4 = *(const float4*)(bias + nb);
    float sv[4] = {0.f, 0.f, 0.f, 0.f}, qv[4] = {0.f, 0.f, 0.f, 0.f};
#pragma unroll
    for (int mi = 0; mi < 4; ++mi) {
      const int row = m0 + wr * 64 + mi * 16 + fm;
      if (row < NN) {
        float v0 = acc[mi][ni].x + b4.x;
        float v1 = acc[mi][ni].y + b4.y;
        float v2 = acc[mi][ni].z + b4.z;
        float v3 = acc[mi][ni].w + b4.w;
        *(float4*)(h2f + (size_t)row * 256 + nb) = make_float4(v0, v1, v2, v3);
        sv[0] += v0; sv[1] += v1; sv[2] += v2; sv[3] += v3;
        qv[0] += v0 * v0; qv[1] += v1 * v1; qv[2] += v2 * v2; qv[3] += v3 * v3;
      }
    }
#pragma unroll
    for (int msk = 1; msk < 16; msk <<= 1) {
#pragma unroll
      for (int j = 0; j < 4; ++j) {
        sv[j] += __shfl_xor(sv[j], msk);
        qv[j] += __shfl_xor(qv[j], msk);
      }
    }
    if (fm == 0) {
      const int lc = wc * 64 + ni * 16 + g * 4;
#pragma unroll
      for (int j = 0; j < 4; ++j) {
        atomicAdd(&sS[lc + j], sv[j]);
        atomicAdd(&sQ[lc + j], qv[j]);
      }
    }
  }
  __syncthreads();
  if (t < 128) {
    part_s[(size_t)blockIdx.y * 256 + n0 + t] = sS[t];
    part_q[(size_t)blockIdx.y * 256 + n0 + t] = sQ[t];
  }
}

// -------------------------------------------------------------- BN pieces --
__global__ void k_bnfin(float* __restrict__ stats,
    const float* __restrict__ part_s, const float* __restrict__ part_q,
    const float* __restrict__ g, const float* __restrict__ b) {
  const int c = threadIdx.x;  // 256
  float s = 0.f, q = 0.f;
  for (int r = 0; r < NNP / 128; ++r) {
    s += part_s[r * 256 + c];
    q += part_q[r * 256 + c];
  }
  float mean = s * (1.0f / NN);
  float var = q * (1.0f / NN) - mean * mean;
  float A = g[c] * rsqrtf(var + BN_EPS);
  stats[c] = A;
  stats[256 + c] = b[c] - mean * A;
}

// mode 0: relu -> hh fp16 (next layer); mode 1: final -> hout fp32, no relu
__global__ __launch_bounds__(256) void k_bnapply(
    const float* __restrict__ h2f, const float* __restrict__ stats,
    ushort* __restrict__ hh, float* __restrict__ hout, int mode) {
  const int wid = threadIdx.x >> 6, lane = threadIdx.x & 63;
  const int row = blockIdx.x * 4 + wid;
  const int c = lane << 2;
  float4 v = *(const float4*)(h2f + (size_t)row * EMB + c);
  float4 Av = *(const float4*)(stats + c);
  float4 Bv = *(const float4*)(stats + 256 + c);
  float o0 = fmaf(v.x, Av.x, Bv.x);
  float o1 = fmaf(v.y, Av.y, Bv.y);
  float o2 = fmaf(v.z, Av.z, Bv.z);
  float o3 = fmaf(v.w, Av.w, Bv.w);
  if (mode == 0) {
    ushort4 o;
    o.x = f2h(fmaxf(o0, 0.f)); o.y = f2h(fmaxf(o1, 0.f));
    o.z = f2h(fmaxf(o2, 0.f)); o.w = f2h(fmaxf(o3, 0.f));
    *(ushort4*)(hh + (size_t)row * EMB + c) = o;
  } else {
    *(float4*)(hout + (size_t)row * EMB + c) = make_float4(o0, o1, o2, o3);
  }
}

// ------------------------------------------------------------------ host ---
extern "C" void kernel_launch(void* const* d_in, const int* in_sizes, int n_in,
                              void* d_out, int out_size, void* d_ws, size_t ws_size,
                              hipStream_t stream) {
  const int* x    = (const int*)d_in[0];
  const int* ei   = (const int*)d_in[1];
  const int* ea   = (const int*)d_in[2];
  const float* xe1 = (const float*)d_in[3];
  const float* xe2 = (const float*)d_in[4];
  const float* ee1 = (const float*)d_in[5];
  const float* ee2 = (const float*)d_in[6];
  const float* W1  = (const float*)d_in[7];   // [L][256][512]
  const float* b1  = (const float*)d_in[8];   // [L][512]
  const float* W2  = (const float*)d_in[9];   // [L][512][256]
  const float* b2  = (const float*)d_in[10];  // [L][256]
  const float* bng = (const float*)d_in[11];
  const float* bnb = (const float*)d_in[12];

  char* ws = (char*)d_ws;
  size_t off = 0;
  float* h2f = (float*)(ws + off);            // [NNP][256] f32
  ushort* aggh = (ushort*)(ws + off);         // aliases h2f (disjoint in time)
  off += (size_t)NNP * 256 * 4;
  ushort* hid = (ushort*)(ws + off); off += (size_t)NNP * 512 * 2;
  ushort* hh  = (ushort*)(ws + off); off += (size_t)NNP * 256 * 2;
  ushort* w1t = (ushort*)(ws + off); off += (size_t)NL * 512 * 256 * 2;
  ushort* w2t = (ushort*)(ws + off); off += (size_t)NL * 256 * 512 * 2;
  float* ecomb = (float*)(ws + off); off += (size_t)NL * 10 * EMB * 4;
  float* stats = (float*)(ws + off); off += 512 * 4;
  float* part_s = (float*)(ws + off); off += (size_t)(NNP / 128) * 256 * 4;
  float* part_q = (float*)(ws + off); off += (size_t)(NNP / 128) * 256 * 4;
  int* rowptr = (int*)(ws + off); off += (size_t)(NN + 1) * 4;
  int* cursor = (int*)(ws + off); off += (size_t)NN * 4;
  int* ebuf   = (int*)(ws + off); off += (size_t)NE * 4;
  int* deg = ebuf;   // alias: deg dead before ebuf written

  // one-time prep
  hipMemsetAsync(deg, 0, NN * sizeof(int), stream);
  k_hist<<<(NE + 255) / 256, 256, 0, stream>>>(deg, ei);
  k_scan<<<1, 1024, 0, stream>>>(deg, rowptr, cursor);
  k_bucket<<<(NE + 255) / 256, 256, 0, stream>>>(ebuf, cursor, ei, ea);
  k_sortseg<<<(NN + 255) / 256, 256, 0, stream>>>(ebuf, rowptr);
  k_ecomb<<<NL * 10, 256, 0, stream>>>(ecomb, ee1, ee2);
  for (int l = 0; l < NL; ++l) {
    k_wt<<<dim3(512 / 32, 256 / 32), 256, 0, stream>>>(
        W1 + (size_t)l * 256 * 512, w1t + (size_t)l * 512 * 256, 256, 512);
    k_wt<<<dim3(256 / 32, 512 / 32), 256, 0, stream>>>(
        W2 + (size_t)l * 512 * 256, w2t + (size_t)l * 256 * 512, 512, 256);
  }
  k_embed<<<NN / 4, 256, 0, stream>>>(hh, x, xe1, xe2);

  for (int l = 0; l < NL; ++l) {
    k_gather<<<NN / 4, 256, 0, stream>>>(aggh, hh, rowptr, ebuf,
                                         ecomb + (size_t)l * 10 * EMB);
    k_mfma1<<<dim3(4, NNP / 128), 256, 0, stream>>>(
        aggh, w1t + (size_t)l * 512 * 256, b1 + (size_t)l * 512, hid);
    k_mfma2<<<dim3(2, NNP / 128), 256, 0, stream>>>(
        hid, w2t + (size_t)l * 256 * 512, b2 + (size_t)l * 256, h2f,
        part_s, part_q);
    k_bnfin<<<1, 256, 0, stream>>>(stats, part_s, part_q,
                                   bng + (size_t)l * EMB, bnb + (size_t)l * EMB);
    k_bnapply<<<NN / 4, 256, 0, stream>>>(h2f, stats, hh, (float*)d_out,
                                          l == NL - 1 ? 1 : 0);
  }
}

// Round 8
// 2724.417 us; speedup vs baseline: 3.3067x; 1.1275x over previous
//
#include <hip/hip_runtime.h>

#define NN 100000
#define NNP 100096          // padded to multiple of 128
#define NE 300000
#define EMB 256
#define NL 5
#define BN_EPS 1e-5f

typedef __attribute__((ext_vector_type(8))) _Float16 half8;
typedef __attribute__((ext_vector_type(4))) float f32x4;

__device__ __forceinline__ ushort f2h(float f) {
  _Float16 h = (_Float16)f;
  return *(ushort*)&h;
}
__device__ __forceinline__ float h2f(ushort u) {
  _Float16 h = *(_Float16*)&u;
  return (float)h;
}

// XOR-swizzled LDS address (G4 recipe): row stride 128 B, bytecol 16B-aligned
__device__ __forceinline__ ushort* lds_at(ushort* base, int row, int bytecol) {
  return (ushort*)((char*)base + row * 128 + (bytecol ^ ((row & 7) << 4)));
}
// C-tile staging: row stride 256 B (128 fp16 cols), same XOR family
__device__ __forceinline__ ushort* lds_ct(ushort* base, int row, int bytecol) {
  return (ushort*)((char*)base + row * 256 + (bytecol ^ ((row & 7) << 4)));
}

// ---------------------------------------------------------------- embed ----
__global__ __launch_bounds__(256) void k_embed(ushort* __restrict__ hh,
    const int* __restrict__ x, const float* __restrict__ xe1,
    const float* __restrict__ xe2) {
  const int wid = threadIdx.x >> 6, lane = threadIdx.x & 63;
  const int row = blockIdx.x * 4 + wid;
  const int c = lane << 2;
  const int x0 = x[row * 2], x1 = x[row * 2 + 1];
  float4 a = *(const float4*)(xe1 + (size_t)x0 * EMB + c);
  float4 b = *(const float4*)(xe2 + (size_t)x1 * EMB + c);
  ushort4 o;
  o.x = f2h(a.x + b.x); o.y = f2h(a.y + b.y);
  o.z = f2h(a.z + b.z); o.w = f2h(a.w + b.w);
  *(ushort4*)(hh + (size_t)row * EMB + c) = o;
}

// -------------------------------------------------------------- CSR build --
__global__ __launch_bounds__(256) void k_hist(int* __restrict__ deg,
    const int* __restrict__ ei) {
  int e = blockIdx.x * 256 + threadIdx.x;
  if (e < NE) atomicAdd(&deg[ei[NE + e]], 1);
}

__global__ __launch_bounds__(1024) void k_scan(const int* __restrict__ deg,
    int* __restrict__ rowptr, int* __restrict__ cursor) {
  __shared__ int wsum[16], woff[17];
  const int t = threadIdx.x;
  const int lane = t & 63, w = t >> 6;
  int base = 0;
  for (int start = 0; start < NN; start += 1024) {
    const int i = start + t;
    const int v0 = (i < NN) ? deg[i] : 0;
    int v = v0;
#pragma unroll
    for (int off = 1; off < 64; off <<= 1) {
      int x = __shfl_up(v, off);
      if (lane >= off) v += x;
    }
    if (lane == 63) wsum[w] = v;
    __syncthreads();
    if (t == 0) {
      int s = 0;
#pragma unroll
      for (int k = 0; k < 16; ++k) { woff[k] = s; s += wsum[k]; }
      woff[16] = s;
    }
    __syncthreads();
    if (i < NN) {
      int excl = base + woff[w] + v - v0;
      rowptr[i] = excl;
      cursor[i] = excl;
    }
    base += woff[16];
    __syncthreads();
  }
  if (t == 0) rowptr[NN] = base;
}

__global__ __launch_bounds__(256) void k_bucket(int* __restrict__ ebuf,
    int* __restrict__ cursor, const int* __restrict__ ei,
    const int* __restrict__ ea) {
  int e = blockIdx.x * 256 + threadIdx.x;
  if (e >= NE) return;
  int src = ei[e], dst = ei[NE + e];
  int c9 = ea[e * 2] * 3 + ea[e * 2 + 1];
  int pos = atomicAdd(&cursor[dst], 1);
  ebuf[pos] = src | (c9 << 20);
}

// canonical per-node order -> bit-deterministic gather summation
__global__ __launch_bounds__(256) void k_sortseg(int* __restrict__ ebuf,
    const int* __restrict__ rowptr) {
  int i = blockIdx.x * 256 + threadIdx.x;
  if (i >= NN) return;
  const int beg = rowptr[i], end = rowptr[i + 1];
  for (int a = beg + 1; a < end; ++a) {
    int v = ebuf[a];
    int b = a - 1;
    while (b >= beg && ebuf[b] > v) { ebuf[b + 1] = ebuf[b]; --b; }
    ebuf[b + 1] = v;
  }
}

// ecomb[l][k][c]: k<9 -> e1[k/3]+e2[k%3]; k==9 -> self-loop e1[4]+e2[0]
__global__ __launch_bounds__(256) void k_ecomb(float* __restrict__ ecomb,
    const float* __restrict__ ee1, const float* __restrict__ ee2) {
  const int c = threadIdx.x;
  const int l = blockIdx.x / 10, k = blockIdx.x % 10;
  const float* e1l = ee1 + (size_t)l * 5 * EMB;
  const float* e2l = ee2 + (size_t)l * 3 * EMB;
  float v = (k < 9) ? (e1l[(k / 3) * EMB + c] + e2l[(k % 3) * EMB + c])
                    : (e1l[4 * EMB + c] + e2l[c]);
  ecomb[(size_t)blockIdx.x * EMB + c] = v;
}

// ------------------------------------------- weight transpose + fp16 cast --
__global__ __launch_bounds__(256) void k_wt(const float* __restrict__ src,
    ushort* __restrict__ dst, int R, int C) {
  __shared__ float tile[32][33];
  const int t = threadIdx.x;
  const int tr = t >> 5, tc = t & 31;
  const int r0 = blockIdx.y * 32, c0 = blockIdx.x * 32;
#pragma unroll
  for (int i = 0; i < 4; ++i)
    tile[tr + 8 * i][tc] = src[(size_t)(r0 + tr + 8 * i) * C + c0 + tc];
  __syncthreads();
#pragma unroll
  for (int i = 0; i < 4; ++i)
    dst[(size_t)(c0 + tr + 8 * i) * R + r0 + tc] = f2h(tile[tc][tr + 8 * i]);
}

// --------------------------------------------------- gather aggregation ----
__global__ __launch_bounds__(256) void k_gather(ushort* __restrict__ aggh,
    const ushort* __restrict__ hh, const int* __restrict__ rowptr,
    const int* __restrict__ ebuf, const float* __restrict__ ecomb) {
  const int wid = threadIdx.x >> 6, lane = threadIdx.x & 63;
  const int i = blockIdx.x * 4 + wid;
  const int c = lane << 2;
  ushort4 hv = *(const ushort4*)(hh + (size_t)i * EMB + c);
  float4 sv = *(const float4*)(ecomb + 9 * EMB + c);
  float sx = h2f(hv.x) + sv.x, sy = h2f(hv.y) + sv.y;
  float sz = h2f(hv.z) + sv.z, sw = h2f(hv.w) + sv.w;
  const int beg = rowptr[i], end = rowptr[i + 1];
  for (int j = beg; j < end; ++j) {
    int p = ebuf[j];
    int src = p & 0xFFFFF, c9 = p >> 20;
    ushort4 a = *(const ushort4*)(hh + (size_t)src * EMB + c);
    float4 b = *(const float4*)(ecomb + (size_t)c9 * EMB + c);
    sx += h2f(a.x) + b.x; sy += h2f(a.y) + b.y;
    sz += h2f(a.z) + b.z; sw += h2f(a.w) + b.w;
  }
  ushort4 o;
  o.x = f2h(sx); o.y = f2h(sy); o.z = f2h(sz); o.w = f2h(sw);
  *(ushort4*)(aggh + (size_t)i * EMB + c) = o;
}

// ------------------------------------------------------- MFMA fp16 GEMMs ---
// 128x128 tile, BK=64, 4 waves (2x2), 64x64 per wave. Swapped mfma(B,A).
// Epilogue: stage fp16 C-tile in LDS (aliasing As/Bs), then read back so each
// store instruction writes 16 FULL 64-B lines (4 lanes x 16 B per row) ->
// no partial-line RMW, write amplification ~1x.

// GEMM1: C[NNP][512] = relu(A[NNP][256] @ W1 + b1)
__global__ __launch_bounds__(256) void k_mfma1(
    const ushort* __restrict__ A, const ushort* __restrict__ BT,
    const float* __restrict__ bias, ushort* __restrict__ C) {
  __shared__ ushort smem[16384];           // As | Bs, reused as 128x128 C-tile
  ushort* As = smem;                       // [128][64]
  ushort* Bs = smem + 8192;                // [128][64]
  const int t = threadIdx.x;
  const int lane = t & 63, w = t >> 6;
  const int wr = w >> 1, wc = w & 1;
  const int m0 = blockIdx.y * 128, n0 = blockIdx.x * 128;
  const int r0 = t >> 3, kc = (t & 7) * 8;
  const int fm = lane & 15, g = lane >> 4;
  f32x4 acc[4][4];
#pragma unroll
  for (int i = 0; i < 4; ++i)
#pragma unroll
    for (int j = 0; j < 4; ++j) acc[i][j] = (f32x4){0.f, 0.f, 0.f, 0.f};

  for (int k0 = 0; k0 < 256; k0 += 64) {
    uint4 av[4], bv[4];
#pragma unroll
    for (int i = 0; i < 4; ++i) {
      av[i] = *(const uint4*)(A + (size_t)(m0 + r0 + 32 * i) * 256 + k0 + kc);
      bv[i] = *(const uint4*)(BT + (size_t)(n0 + r0 + 32 * i) * 256 + k0 + kc);
    }
    __syncthreads();
#pragma unroll
    for (int i = 0; i < 4; ++i) {
      *(uint4*)lds_at(As, r0 + 32 * i, kc * 2) = av[i];
      *(uint4*)lds_at(Bs, r0 + 32 * i, kc * 2) = bv[i];
    }
    __syncthreads();
#pragma unroll
    for (int kk = 0; kk < 2; ++kk) {
      half8 af[4], bf[4];
#pragma unroll
      for (int mi = 0; mi < 4; ++mi)
        af[mi] = *(const half8*)lds_at(As, wr * 64 + mi * 16 + fm,
                                       kk * 64 + g * 16);
#pragma unroll
      for (int ni = 0; ni < 4; ++ni)
        bf[ni] = *(const half8*)lds_at(Bs, wc * 64 + ni * 16 + fm,
                                       kk * 64 + g * 16);
#pragma unroll
      for (int mi = 0; mi < 4; ++mi)
#pragma unroll
        for (int ni = 0; ni < 4; ++ni)
          acc[mi][ni] = __builtin_amdgcn_mfma_f32_16x16x32_f16(
              bf[ni], af[mi], acc[mi][ni], 0, 0, 0);
    }
    __syncthreads();
  }
  // ---- stage C tile (bias+relu+fp16) into LDS ----
#pragma unroll
  for (int ni = 0; ni < 4; ++ni) {
    const int col = wc * 64 + ni * 16 + g * 4;
    const float4 b4 = *(const float4*)(bias + n0 + col);
#pragma unroll
    for (int mi = 0; mi < 4; ++mi) {
      const int row = wr * 64 + mi * 16 + fm;
      ushort4 o;
      o.x = f2h(fmaxf(acc[mi][ni].x + b4.x, 0.f));
      o.y = f2h(fmaxf(acc[mi][ni].y + b4.y, 0.f));
      o.z = f2h(fmaxf(acc[mi][ni].z + b4.z, 0.f));
      o.w = f2h(fmaxf(acc[mi][ni].w + b4.w, 0.f));
      *(ushort4*)lds_ct(smem, row, col * 2) = o;
    }
  }
  __syncthreads();
  // ---- coalesced store: 4 lanes cover one full 64-B line per row ----
#pragma unroll
  for (int rr = 0; rr < 2; ++rr) {
    const int row = rr * 64 + (t >> 2);
    const int grow = m0 + row;
    if (grow < NN) {
#pragma unroll
      for (int it = 0; it < 4; ++it) {
        const int bc = it * 64 + (t & 3) * 16;
        uint4 v = *(const uint4*)lds_ct(smem, row, bc);
        *(uint4*)((char*)(C + (size_t)grow * 512 + n0) + bc) = v;
      }
    }
  }
}

// GEMM2: hh2[NNP][256] = A[NNP][512] @ W2 + b2 (fp16 out) + BN partials (fp32)
__global__ __launch_bounds__(256) void k_mfma2(
    const ushort* __restrict__ A, const ushort* __restrict__ BT,
    const float* __restrict__ bias, ushort* __restrict__ hh2,
    float* __restrict__ part_s, float* __restrict__ part_q) {
  __shared__ ushort smem[16384];
  __shared__ float sS[128], sQ[128];
  ushort* As = smem;
  ushort* Bs = smem + 8192;
  const int t = threadIdx.x;
  if (t < 128) { sS[t] = 0.f; sQ[t] = 0.f; }
  const int lane = t & 63, w = t >> 6;
  const int wr = w >> 1, wc = w & 1;
  const int m0 = blockIdx.y * 128, n0 = blockIdx.x * 128;
  const int r0 = t >> 3, kc = (t & 7) * 8;
  const int fm = lane & 15, g = lane >> 4;
  f32x4 acc[4][4];
#pragma unroll
  for (int i = 0; i < 4; ++i)
#pragma unroll
    for (int j = 0; j < 4; ++j) acc[i][j] = (f32x4){0.f, 0.f, 0.f, 0.f};

  for (int k0 = 0; k0 < 512; k0 += 64) {
    uint4 av[4], bv[4];
#pragma unroll
    for (int i = 0; i < 4; ++i) {
      av[i] = *(const uint4*)(A + (size_t)(m0 + r0 + 32 * i) * 512 + k0 + kc);
      bv[i] = *(const uint4*)(BT + (size_t)(n0 + r0 + 32 * i) * 512 + k0 + kc);
    }
    __syncthreads();
#pragma unroll
    for (int i = 0; i < 4; ++i) {
      *(uint4*)lds_at(As, r0 + 32 * i, kc * 2) = av[i];
      *(uint4*)lds_at(Bs, r0 + 32 * i, kc * 2) = bv[i];
    }
    __syncthreads();
#pragma unroll
    for (int kk = 0; kk < 2; ++kk) {
      half8 af[4], bf[4];
#pragma unroll
      for (int mi = 0; mi < 4; ++mi)
        af[mi] = *(const half8*)lds_at(As, wr * 64 + mi * 16 + fm,
                                       kk * 64 + g * 16);
#pragma unroll
      for (int ni = 0; ni < 4; ++ni)
        bf[ni] = *(const half8*)lds_at(Bs, wc * 64 + ni * 16 + fm,
                                       kk * 64 + g * 16);
#pragma unroll
      for (int mi = 0; mi < 4; ++mi)
#pragma unroll
        for (int ni = 0; ni < 4; ++ni)
          acc[mi][ni] = __builtin_amdgcn_mfma_f32_16x16x32_f16(
              bf[ni], af[mi], acc[mi][ni], 0, 0, 0);
    }
    __syncthreads();
  }
  // ---- stats (exact fp32) + stage fp16 C tile ----
#pragma unroll
  for (int ni = 0; ni < 4; ++ni) {
    const int col = wc * 64 + ni * 16 + g * 4;
    const float4 b4 = *(const float4*)(bias + n0 + col);
    float sv[4] = {0.f, 0.f, 0.f, 0.f}, qv[4] = {0.f, 0.f, 0.f, 0.f};
#pragma unroll
    for (int mi = 0; mi < 4; ++mi) {
      const int row = wr * 64 + mi * 16 + fm;
      const float v0 = acc[mi][ni].x + b4.x;
      const float v1 = acc[mi][ni].y + b4.y;
      const float v2 = acc[mi][ni].z + b4.z;
      const float v3 = acc[mi][ni].w + b4.w;
      if (m0 + row < NN) {
        sv[0] += v0; sv[1] += v1; sv[2] += v2; sv[3] += v3;
        qv[0] += v0 * v0; qv[1] += v1 * v1; qv[2] += v2 * v2; qv[3] += v3 * v3;
      }
      ushort4 o;
      o.x = f2h(v0); o.y = f2h(v1); o.z = f2h(v2); o.w = f2h(v3);
      *(ushort4*)lds_ct(smem, row, col * 2) = o;
    }
#pragma unroll
    for (int msk = 1; msk < 16; msk <<= 1) {
#pragma unroll
      for (int j = 0; j < 4; ++j) {
        sv[j] += __shfl_xor(sv[j], msk);
        qv[j] += __shfl_xor(qv[j], msk);
      }
    }
    if (fm == 0) {
#pragma unroll
      for (int j = 0; j < 4; ++j) {
        atomicAdd(&sS[col + j], sv[j]);
        atomicAdd(&sQ[col + j], qv[j]);
      }
    }
  }
  __syncthreads();
  // ---- coalesced fp16 store ----
#pragma unroll
  for (int rr = 0; rr < 2; ++rr) {
    const int row = rr * 64 + (t >> 2);
    const int grow = m0 + row;
    if (grow < NN) {
#pragma unroll
      for (int it = 0; it < 4; ++it) {
        const int bc = it * 64 + (t & 3) * 16;
        uint4 v = *(const uint4*)lds_ct(smem, row, bc);
        *(uint4*)((char*)(hh2 + (size_t)grow * 256 + n0) + bc) = v;
      }
    }
  }
  if (t < 128) {
    part_s[(size_t)blockIdx.y * 256 + n0 + t] = sS[t];
    part_q[(size_t)blockIdx.y * 256 + n0 + t] = sQ[t];
  }
}

// -------------------------------------------------------------- BN pieces --
__global__ void k_bnfin(float* __restrict__ stats,
    const float* __restrict__ part_s, const float* __restrict__ part_q,
    const float* __restrict__ g, const float* __restrict__ b) {
  const int c = threadIdx.x;  // 256
  float s = 0.f, q = 0.f;
  for (int r = 0; r < NNP / 128; ++r) {
    s += part_s[r * 256 + c];
    q += part_q[r * 256 + c];
  }
  float mean = s * (1.0f / NN);
  float var = q * (1.0f / NN) - mean * mean;
  float A = g[c] * rsqrtf(var + BN_EPS);
  stats[c] = A;
  stats[256 + c] = b[c] - mean * A;
}

// mode 0: relu -> hh fp16 (next layer); mode 1: final -> hout fp32, no relu
__global__ __launch_bounds__(256) void k_bnapply(
    const ushort* __restrict__ hh2, const float* __restrict__ stats,
    ushort* __restrict__ hh, float* __restrict__ hout, int mode) {
  const int wid = threadIdx.x >> 6, lane = threadIdx.x & 63;
  const int row = blockIdx.x * 4 + wid;
  const int c = lane << 2;
  ushort4 v4 = *(const ushort4*)(hh2 + (size_t)row * EMB + c);
  float4 Av = *(const float4*)(stats + c);
  float4 Bv = *(const float4*)(stats + 256 + c);
  float o0 = fmaf(h2f(v4.x), Av.x, Bv.x);
  float o1 = fmaf(h2f(v4.y), Av.y, Bv.y);
  float o2 = fmaf(h2f(v4.z), Av.z, Bv.z);
  float o3 = fmaf(h2f(v4.w), Av.w, Bv.w);
  if (mode == 0) {
    ushort4 o;
    o.x = f2h(fmaxf(o0, 0.f)); o.y = f2h(fmaxf(o1, 0.f));
    o.z = f2h(fmaxf(o2, 0.f)); o.w = f2h(fmaxf(o3, 0.f));
    *(ushort4*)(hh + (size_t)row * EMB + c) = o;
  } else {
    *(float4*)(hout + (size_t)row * EMB + c) = make_float4(o0, o1, o2, o3);
  }
}

// ------------------------------------------------------------------ host ---
extern "C" void kernel_launch(void* const* d_in, const int* in_sizes, int n_in,
                              void* d_out, int out_size, void* d_ws, size_t ws_size,
                              hipStream_t stream) {
  const int* x    = (const int*)d_in[0];
  const int* ei   = (const int*)d_in[1];
  const int* ea   = (const int*)d_in[2];
  const float* xe1 = (const float*)d_in[3];
  const float* xe2 = (const float*)d_in[4];
  const float* ee1 = (const float*)d_in[5];
  const float* ee2 = (const float*)d_in[6];
  const float* W1  = (const float*)d_in[7];   // [L][256][512]
  const float* b1  = (const float*)d_in[8];   // [L][512]
  const float* W2  = (const float*)d_in[9];   // [L][512][256]
  const float* b2  = (const float*)d_in[10];  // [L][256]
  const float* bng = (const float*)d_in[11];
  const float* bnb = (const float*)d_in[12];

  char* ws = (char*)d_ws;
  size_t off = 0;
  ushort* aggh = (ushort*)(ws + off); off += (size_t)NNP * 256 * 2;
  ushort* hh2  = (ushort*)(ws + off); off += (size_t)NNP * 256 * 2;
  ushort* hid  = (ushort*)(ws + off); off += (size_t)NNP * 512 * 2;
  ushort* hh   = (ushort*)(ws + off); off += (size_t)NNP * 256 * 2;
  ushort* w1t  = (ushort*)(ws + off); off += (size_t)NL * 512 * 256 * 2;
  ushort* w2t  = (ushort*)(ws + off); off += (size_t)NL * 256 * 512 * 2;
  float* ecomb = (float*)(ws + off); off += (size_t)NL * 10 * EMB * 4;
  float* stats = (float*)(ws + off); off += 512 * 4;
  float* part_s = (float*)(ws + off); off += (size_t)(NNP / 128) * 256 * 4;
  float* part_q = (float*)(ws + off); off += (size_t)(NNP / 128) * 256 * 4;
  int* rowptr = (int*)(ws + off); off += (size_t)(NN + 1) * 4;
  int* cursor = (int*)(ws + off); off += (size_t)NN * 4;
  int* ebuf   = (int*)(ws + off); off += (size_t)NE * 4;
  int* deg = ebuf;   // alias: deg dead before ebuf written

  // one-time prep
  hipMemsetAsync(deg, 0, NN * sizeof(int), stream);
  k_hist<<<(NE + 255) / 256, 256, 0, stream>>>(deg, ei);
  k_scan<<<1, 1024, 0, stream>>>(deg, rowptr, cursor);
  k_bucket<<<(NE + 255) / 256, 256, 0, stream>>>(ebuf, cursor, ei, ea);
  k_sortseg<<<(NN + 255) / 256, 256, 0, stream>>>(ebuf, rowptr);
  k_ecomb<<<NL * 10, 256, 0, stream>>>(ecomb, ee1, ee2);
  for (int l = 0; l < NL; ++l) {
    k_wt<<<dim3(512 / 32, 256 / 32), 256, 0, stream>>>(
        W1 + (size_t)l * 256 * 512, w1t + (size_t)l * 512 * 256, 256, 512);
    k_wt<<<dim3(256 / 32, 512 / 32), 256, 0, stream>>>(
        W2 + (size_t)l * 512 * 256, w2t + (size_t)l * 256 * 512, 512, 256);
  }
  k_embed<<<NN / 4, 256, 0, stream>>>(hh, x, xe1, xe2);

  for (int l = 0; l < NL; ++l) {
    k_gather<<<NN / 4, 256, 0, stream>>>(aggh, hh, rowptr, ebuf,
                                         ecomb + (size_t)l * 10 * EMB);
    k_mfma1<<<dim3(4, NNP / 128), 256, 0, stream>>>(
        aggh, w1t + (size_t)l * 512 * 256, b1 + (size_t)l * 512, hid);
    k_mfma2<<<dim3(2, NNP / 128), 256, 0, stream>>>(
        hid, w2t + (size_t)l * 256 * 512, b2 + (size_t)l * 256, hh2,
        part_s, part_q);
    k_bnfin<<<1, 256, 0, stream>>>(stats, part_s, part_q,
                                   bng + (size_t)l * EMB, bnb + (size_t)l * EMB);
    k_bnapply<<<NN / 4, 256, 0, stream>>>(hh2, stats, hh, (float*)d_out,
                                          l == NL - 1 ? 1 : 0);
  }
}

// Round 9
// 1772.913 us; speedup vs baseline: 5.0814x; 1.5367x over previous
//
#include <hip/hip_runtime.h>

#define NN 100000
#define NNP 100096          // padded to multiple of 128
#define NE 300000
#define EMB 256
#define NL 5
#define BN_EPS 1e-5f

typedef __attribute__((ext_vector_type(8))) _Float16 half8;
typedef __attribute__((ext_vector_type(4))) float f32x4;

__device__ __forceinline__ ushort f2h(float f) {
  _Float16 h = (_Float16)f;
  return *(ushort*)&h;
}
__device__ __forceinline__ float h2f(ushort u) {
  _Float16 h = *(_Float16*)&u;
  return (float)h;
}

// direct global->LDS DMA, 16 B per lane (no VGPR round-trip, nothing to spill)
__device__ __forceinline__ void gl2lds16(const ushort* g, ushort* l) {
  __builtin_amdgcn_global_load_lds(
      (const __attribute__((address_space(1))) void*)g,
      (__attribute__((address_space(3))) void*)l, 16, 0, 0);
}

// XOR-swizzled LDS read address: row stride 128 B, chunk ^= (row&7)
__device__ __forceinline__ ushort* lds_at(ushort* base, int row, int bytecol) {
  return (ushort*)((char*)base + row * 128 + (bytecol ^ ((row & 7) << 4)));
}
// C-tile staging: row stride 256 B, same XOR family
__device__ __forceinline__ ushort* lds_ct(ushort* base, int row, int bytecol) {
  return (ushort*)((char*)base + row * 256 + (bytecol ^ ((row & 7) << 4)));
}

// ---------------------------------------------------------------- embed ----
__global__ __launch_bounds__(256) void k_embed(ushort* __restrict__ hh,
    const int* __restrict__ x, const float* __restrict__ xe1,
    const float* __restrict__ xe2) {
  const int wid = threadIdx.x >> 6, lane = threadIdx.x & 63;
  const int row = blockIdx.x * 4 + wid;
  const int c = lane << 2;
  const int x0 = x[row * 2], x1 = x[row * 2 + 1];
  float4 a = *(const float4*)(xe1 + (size_t)x0 * EMB + c);
  float4 b = *(const float4*)(xe2 + (size_t)x1 * EMB + c);
  ushort4 o;
  o.x = f2h(a.x + b.x); o.y = f2h(a.y + b.y);
  o.z = f2h(a.z + b.z); o.w = f2h(a.w + b.w);
  *(ushort4*)(hh + (size_t)row * EMB + c) = o;
}

// -------------------------------------------------------------- CSR build --
__global__ __launch_bounds__(256) void k_hist(int* __restrict__ deg,
    const int* __restrict__ ei) {
  int e = blockIdx.x * 256 + threadIdx.x;
  if (e < NE) atomicAdd(&deg[ei[NE + e]], 1);
}

__global__ __launch_bounds__(1024) void k_scan(const int* __restrict__ deg,
    int* __restrict__ rowptr, int* __restrict__ cursor) {
  __shared__ int wsum[16], woff[17];
  const int t = threadIdx.x;
  const int lane = t & 63, w = t >> 6;
  int base = 0;
  for (int start = 0; start < NN; start += 1024) {
    const int i = start + t;
    const int v0 = (i < NN) ? deg[i] : 0;
    int v = v0;
#pragma unroll
    for (int off = 1; off < 64; off <<= 1) {
      int x = __shfl_up(v, off);
      if (lane >= off) v += x;
    }
    if (lane == 63) wsum[w] = v;
    __syncthreads();
    if (t == 0) {
      int s = 0;
#pragma unroll
      for (int k = 0; k < 16; ++k) { woff[k] = s; s += wsum[k]; }
      woff[16] = s;
    }
    __syncthreads();
    if (i < NN) {
      int excl = base + woff[w] + v - v0;
      rowptr[i] = excl;
      cursor[i] = excl;
    }
    base += woff[16];
    __syncthreads();
  }
  if (t == 0) rowptr[NN] = base;
}

__global__ __launch_bounds__(256) void k_bucket(int* __restrict__ ebuf,
    int* __restrict__ cursor, const int* __restrict__ ei,
    const int* __restrict__ ea) {
  int e = blockIdx.x * 256 + threadIdx.x;
  if (e >= NE) return;
  int src = ei[e], dst = ei[NE + e];
  int c9 = ea[e * 2] * 3 + ea[e * 2 + 1];
  int pos = atomicAdd(&cursor[dst], 1);
  ebuf[pos] = src | (c9 << 20);
}

// canonical per-node order -> bit-deterministic gather summation
__global__ __launch_bounds__(256) void k_sortseg(int* __restrict__ ebuf,
    const int* __restrict__ rowptr) {
  int i = blockIdx.x * 256 + threadIdx.x;
  if (i >= NN) return;
  const int beg = rowptr[i], end = rowptr[i + 1];
  for (int a = beg + 1; a < end; ++a) {
    int v = ebuf[a];
    int b = a - 1;
    while (b >= beg && ebuf[b] > v) { ebuf[b + 1] = ebuf[b]; --b; }
    ebuf[b + 1] = v;
  }
}

// ecomb[l][k][c]: k<9 -> e1[k/3]+e2[k%3]; k==9 -> self-loop e1[4]+e2[0]
__global__ __launch_bounds__(256) void k_ecomb(float* __restrict__ ecomb,
    const float* __restrict__ ee1, const float* __restrict__ ee2) {
  const int c = threadIdx.x;
  const int l = blockIdx.x / 10, k = blockIdx.x % 10;
  const float* e1l = ee1 + (size_t)l * 5 * EMB;
  const float* e2l = ee2 + (size_t)l * 3 * EMB;
  float v = (k < 9) ? (e1l[(k / 3) * EMB + c] + e2l[(k % 3) * EMB + c])
                    : (e1l[4 * EMB + c] + e2l[c]);
  ecomb[(size_t)blockIdx.x * EMB + c] = v;
}

// ------------------------------------------- weight transpose + fp16 cast --
__global__ __launch_bounds__(256) void k_wt(const float* __restrict__ src,
    ushort* __restrict__ dst, int R, int C) {
  __shared__ float tile[32][33];
  const int t = threadIdx.x;
  const int tr = t >> 5, tc = t & 31;
  const int r0 = blockIdx.y * 32, c0 = blockIdx.x * 32;
#pragma unroll
  for (int i = 0; i < 4; ++i)
    tile[tr + 8 * i][tc] = src[(size_t)(r0 + tr + 8 * i) * C + c0 + tc];
  __syncthreads();
#pragma unroll
  for (int i = 0; i < 4; ++i)
    dst[(size_t)(c0 + tr + 8 * i) * R + r0 + tc] = f2h(tile[tc][tr + 8 * i]);
}

// --------------------------------------------------- gather aggregation ----
__global__ __launch_bounds__(256) void k_gather(ushort* __restrict__ aggh,
    const ushort* __restrict__ hh, const int* __restrict__ rowptr,
    const int* __restrict__ ebuf, const float* __restrict__ ecomb) {
  const int wid = threadIdx.x >> 6, lane = threadIdx.x & 63;
  const int i = blockIdx.x * 4 + wid;
  const int c = lane << 2;
  ushort4 hv = *(const ushort4*)(hh + (size_t)i * EMB + c);
  float4 sv = *(const float4*)(ecomb + 9 * EMB + c);
  float sx = h2f(hv.x) + sv.x, sy = h2f(hv.y) + sv.y;
  float sz = h2f(hv.z) + sv.z, sw = h2f(hv.w) + sv.w;
  const int beg = rowptr[i], end = rowptr[i + 1];
  for (int j = beg; j < end; ++j) {
    int p = ebuf[j];
    int src = p & 0xFFFFF, c9 = p >> 20;
    ushort4 a = *(const ushort4*)(hh + (size_t)src * EMB + c);
    float4 b = *(const float4*)(ecomb + (size_t)c9 * EMB + c);
    sx += h2f(a.x) + b.x; sy += h2f(a.y) + b.y;
    sz += h2f(a.z) + b.z; sw += h2f(a.w) + b.w;
  }
  ushort4 o;
  o.x = f2h(sx); o.y = f2h(sy); o.z = f2h(sz); o.w = f2h(sw);
  *(ushort4*)(aggh + (size_t)i * EMB + c) = o;
}

// ------------------------------------------------------- MFMA fp16 GEMMs ---
// 128x128 tile, BK=64, 4 waves (2x2). Staging: global_load_lds DMA, LDS dest
// linear, global source pre-swizzled (chunk ^= row&7) so swizzled ds_read
// (lds_at) sees logical layout. No staging VGPRs -> no spills.

// GEMM1: C[NNP][512] = relu(A[NNP][256] @ W1 + b1)
__global__ __launch_bounds__(256) void k_mfma1(
    const ushort* __restrict__ A, const ushort* __restrict__ BT,
    const float* __restrict__ bias, ushort* __restrict__ C) {
  __shared__ ushort smem[16384];           // As | Bs, reused as 128x128 C-tile
  ushort* As = smem;                       // [128][64] fp16, 16 KB
  ushort* Bs = smem + 8192;
  const int t = threadIdx.x;
  const int lane = t & 63, w = t >> 6;
  const int wr = w >> 1, wc = w & 1;
  const int m0 = blockIdx.y * 128, n0 = blockIdx.x * 128;
  const int fm = lane & 15, g = lane >> 4;
  const int r_loc = lane >> 3, gchunk = (lane & 7) ^ r_loc;  // source swizzle
  f32x4 acc[4][4];
#pragma unroll
  for (int i = 0; i < 4; ++i)
#pragma unroll
    for (int j = 0; j < 4; ++j) acc[i][j] = (f32x4){0.f, 0.f, 0.f, 0.f};

  for (int k0 = 0; k0 < 256; k0 += 64) {
#pragma unroll
    for (int i = 0; i < 4; ++i) {
      const int seg = w * 4 + i;           // 8 rows per segment
      const int row = 8 * seg + r_loc;
      gl2lds16(A + (size_t)(m0 + row) * 256 + k0 + gchunk * 8, As + seg * 512);
      gl2lds16(BT + (size_t)(n0 + row) * 256 + k0 + gchunk * 8, Bs + seg * 512);
    }
    __syncthreads();                        // drains vmcnt -> LDS ready
#pragma unroll
    for (int kk = 0; kk < 2; ++kk) {
      half8 af[4], bf[4];
#pragma unroll
      for (int mi = 0; mi < 4; ++mi)
        af[mi] = *(const half8*)lds_at(As, wr * 64 + mi * 16 + fm,
                                       kk * 64 + g * 16);
#pragma unroll
      for (int ni = 0; ni < 4; ++ni)
        bf[ni] = *(const half8*)lds_at(Bs, wc * 64 + ni * 16 + fm,
                                       kk * 64 + g * 16);
#pragma unroll
      for (int mi = 0; mi < 4; ++mi)
#pragma unroll
        for (int ni = 0; ni < 4; ++ni)
          acc[mi][ni] = __builtin_amdgcn_mfma_f32_16x16x32_f16(
              bf[ni], af[mi], acc[mi][ni], 0, 0, 0);
    }
    __syncthreads();                        // compute done before next stage
  }
  // ---- stage C tile (bias+relu+fp16) into LDS ----
#pragma unroll
  for (int ni = 0; ni < 4; ++ni) {
    const int col = wc * 64 + ni * 16 + g * 4;
    const float4 b4 = *(const float4*)(bias + n0 + col);
#pragma unroll
    for (int mi = 0; mi < 4; ++mi) {
      const int row = wr * 64 + mi * 16 + fm;
      ushort4 o;
      o.x = f2h(fmaxf(acc[mi][ni].x + b4.x, 0.f));
      o.y = f2h(fmaxf(acc[mi][ni].y + b4.y, 0.f));
      o.z = f2h(fmaxf(acc[mi][ni].z + b4.z, 0.f));
      o.w = f2h(fmaxf(acc[mi][ni].w + b4.w, 0.f));
      *(ushort4*)lds_ct(smem, row, col * 2) = o;
    }
  }
  __syncthreads();
  // ---- coalesced store ----
#pragma unroll
  for (int rr = 0; rr < 2; ++rr) {
    const int row = rr * 64 + (t >> 2);
    const int grow = m0 + row;
    if (grow < NN) {
#pragma unroll
      for (int it = 0; it < 4; ++it) {
        const int bc = it * 64 + (t & 3) * 16;
        uint4 v = *(const uint4*)lds_ct(smem, row, bc);
        *(uint4*)((char*)(C + (size_t)grow * 512 + n0) + bc) = v;
      }
    }
  }
}

// GEMM2: hh2[NNP][256] = A[NNP][512] @ W2 + b2 (fp16 out) + BN partials (fp32)
__global__ __launch_bounds__(256) void k_mfma2(
    const ushort* __restrict__ A, const ushort* __restrict__ BT,
    const float* __restrict__ bias, ushort* __restrict__ hh2,
    float* __restrict__ part_s, float* __restrict__ part_q) {
  __shared__ ushort smem[16384];
  __shared__ float sS[128], sQ[128];
  ushort* As = smem;
  ushort* Bs = smem + 8192;
  const int t = threadIdx.x;
  if (t < 128) { sS[t] = 0.f; sQ[t] = 0.f; }
  const int lane = t & 63, w = t >> 6;
  const int wr = w >> 1, wc = w & 1;
  const int m0 = blockIdx.y * 128, n0 = blockIdx.x * 128;
  const int fm = lane & 15, g = lane >> 4;
  const int r_loc = lane >> 3, gchunk = (lane & 7) ^ r_loc;
  f32x4 acc[4][4];
#pragma unroll
  for (int i = 0; i < 4; ++i)
#pragma unroll
    for (int j = 0; j < 4; ++j) acc[i][j] = (f32x4){0.f, 0.f, 0.f, 0.f};

  for (int k0 = 0; k0 < 512; k0 += 64) {
#pragma unroll
    for (int i = 0; i < 4; ++i) {
      const int seg = w * 4 + i;
      const int row = 8 * seg + r_loc;
      gl2lds16(A + (size_t)(m0 + row) * 512 + k0 + gchunk * 8, As + seg * 512);
      gl2lds16(BT + (size_t)(n0 + row) * 512 + k0 + gchunk * 8, Bs + seg * 512);
    }
    __syncthreads();
#pragma unroll
    for (int kk = 0; kk < 2; ++kk) {
      half8 af[4], bf[4];
#pragma unroll
      for (int mi = 0; mi < 4; ++mi)
        af[mi] = *(const half8*)lds_at(As, wr * 64 + mi * 16 + fm,
                                       kk * 64 + g * 16);
#pragma unroll
      for (int ni = 0; ni < 4; ++ni)
        bf[ni] = *(const half8*)lds_at(Bs, wc * 64 + ni * 16 + fm,
                                       kk * 64 + g * 16);
#pragma unroll
      for (int mi = 0; mi < 4; ++mi)
#pragma unroll
        for (int ni = 0; ni < 4; ++ni)
          acc[mi][ni] = __builtin_amdgcn_mfma_f32_16x16x32_f16(
              bf[ni], af[mi], acc[mi][ni], 0, 0, 0);
    }
    __syncthreads();
  }
  // ---- stats (exact fp32) + stage fp16 C tile ----
#pragma unroll
  for (int ni = 0; ni < 4; ++ni) {
    const int col = wc * 64 + ni * 16 + g * 4;
    const float4 b4 = *(const float4*)(bias + n0 + col);
    float sv[4] = {0.f, 0.f, 0.f, 0.f}, qv[4] = {0.f, 0.f, 0.f, 0.f};
#pragma unroll
    for (int mi = 0; mi < 4; ++mi) {
      const int row = wr * 64 + mi * 16 + fm;
      const float v0 = acc[mi][ni].x + b4.x;
      const float v1 = acc[mi][ni].y + b4.y;
      const float v2 = acc[mi][ni].z + b4.z;
      const float v3 = acc[mi][ni].w + b4.w;
      if (m0 + row < NN) {
        sv[0] += v0; sv[1] += v1; sv[2] += v2; sv[3] += v3;
        qv[0] += v0 * v0; qv[1] += v1 * v1; qv[2] += v2 * v2; qv[3] += v3 * v3;
      }
      ushort4 o;
      o.x = f2h(v0); o.y = f2h(v1); o.z = f2h(v2); o.w = f2h(v3);
      *(ushort4*)lds_ct(smem, row, col * 2) = o;
    }
#pragma unroll
    for (int msk = 1; msk < 16; msk <<= 1) {
#pragma unroll
      for (int j = 0; j < 4; ++j) {
        sv[j] += __shfl_xor(sv[j], msk);
        qv[j] += __shfl_xor(qv[j], msk);
      }
    }
    if (fm == 0) {
#pragma unroll
      for (int j = 0; j < 4; ++j) {
        atomicAdd(&sS[col + j], sv[j]);
        atomicAdd(&sQ[col + j], qv[j]);
      }
    }
  }
  __syncthreads();
  // ---- coalesced fp16 store ----
#pragma unroll
  for (int rr = 0; rr < 2; ++rr) {
    const int row = rr * 64 + (t >> 2);
    const int grow = m0 + row;
    if (grow < NN) {
#pragma unroll
      for (int it = 0; it < 4; ++it) {
        const int bc = it * 64 + (t & 3) * 16;
        uint4 v = *(const uint4*)lds_ct(smem, row, bc);
        *(uint4*)((char*)(hh2 + (size_t)grow * 256 + n0) + bc) = v;
      }
    }
  }
  if (t < 128) {
    part_s[(size_t)blockIdx.y * 256 + n0 + t] = sS[t];
    part_q[(size_t)blockIdx.y * 256 + n0 + t] = sQ[t];
  }
}

// -------------------------------------------------------------- BN pieces --
__global__ void k_bnfin(float* __restrict__ stats,
    const float* __restrict__ part_s, const float* __restrict__ part_q,
    const float* __restrict__ g, const float* __restrict__ b) {
  const int c = threadIdx.x;  // 256
  float s = 0.f, q = 0.f;
  for (int r = 0; r < NNP / 128; ++r) {
    s += part_s[r * 256 + c];
    q += part_q[r * 256 + c];
  }
  float mean = s * (1.0f / NN);
  float var = q * (1.0f / NN) - mean * mean;
  float A = g[c] * rsqrtf(var + BN_EPS);
  stats[c] = A;
  stats[256 + c] = b[c] - mean * A;
}

// mode 0: relu -> hh fp16 (next layer); mode 1: final -> hout fp32, no relu
__global__ __launch_bounds__(256) void k_bnapply(
    const ushort* __restrict__ hh2, const float* __restrict__ stats,
    ushort* __restrict__ hh, float* __restrict__ hout, int mode) {
  const int wid = threadIdx.x >> 6, lane = threadIdx.x & 63;
  const int row = blockIdx.x * 4 + wid;
  const int c = lane << 2;
  ushort4 v4 = *(const ushort4*)(hh2 + (size_t)row * EMB + c);
  float4 Av = *(const float4*)(stats + c);
  float4 Bv = *(const float4*)(stats + 256 + c);
  float o0 = fmaf(h2f(v4.x), Av.x, Bv.x);
  float o1 = fmaf(h2f(v4.y), Av.y, Bv.y);
  float o2 = fmaf(h2f(v4.z), Av.z, Bv.z);
  float o3 = fmaf(h2f(v4.w), Av.w, Bv.w);
  if (mode == 0) {
    ushort4 o;
    o.x = f2h(fmaxf(o0, 0.f)); o.y = f2h(fmaxf(o1, 0.f));
    o.z = f2h(fmaxf(o2, 0.f)); o.w = f2h(fmaxf(o3, 0.f));
    *(ushort4*)(hh + (size_t)row * EMB + c) = o;
  } else {
    *(float4*)(hout + (size_t)row * EMB + c) = make_float4(o0, o1, o2, o3);
  }
}

// ------------------------------------------------------------------ host ---
extern "C" void kernel_launch(void* const* d_in, const int* in_sizes, int n_in,
                              void* d_out, int out_size, void* d_ws, size_t ws_size,
                              hipStream_t stream) {
  const int* x    = (const int*)d_in[0];
  const int* ei   = (const int*)d_in[1];
  const int* ea   = (const int*)d_in[2];
  const float* xe1 = (const float*)d_in[3];
  const float* xe2 = (const float*)d_in[4];
  const float* ee1 = (const float*)d_in[5];
  const float* ee2 = (const float*)d_in[6];
  const float* W1  = (const float*)d_in[7];   // [L][256][512]
  const float* b1  = (const float*)d_in[8];   // [L][512]
  const float* W2  = (const float*)d_in[9];   // [L][512][256]
  const float* b2  = (const float*)d_in[10];  // [L][256]
  const float* bng = (const float*)d_in[11];
  const float* bnb = (const float*)d_in[12];

  char* ws = (char*)d_ws;
  size_t off = 0;
  ushort* aggh = (ushort*)(ws + off); off += (size_t)NNP * 256 * 2;
  ushort* hh2  = (ushort*)(ws + off); off += (size_t)NNP * 256 * 2;
  ushort* hid  = (ushort*)(ws + off); off += (size_t)NNP * 512 * 2;
  ushort* hh   = (ushort*)(ws + off); off += (size_t)NNP * 256 * 2;
  ushort* w1t  = (ushort*)(ws + off); off += (size_t)NL * 512 * 256 * 2;
  ushort* w2t  = (ushort*)(ws + off); off += (size_t)NL * 256 * 512 * 2;
  float* ecomb = (float*)(ws + off); off += (size_t)NL * 10 * EMB * 4;
  float* stats = (float*)(ws + off); off += 512 * 4;
  float* part_s = (float*)(ws + off); off += (size_t)(NNP / 128) * 256 * 4;
  float* part_q = (float*)(ws + off); off += (size_t)(NNP / 128) * 256 * 4;
  int* rowptr = (int*)(ws + off); off += (size_t)(NN + 1) * 4;
  int* cursor = (int*)(ws + off); off += (size_t)NN * 4;
  int* ebuf   = (int*)(ws + off); off += (size_t)NE * 4;
  int* deg = ebuf;   // alias: deg dead before ebuf written

  // one-time prep
  hipMemsetAsync(deg, 0, NN * sizeof(int), stream);
  k_hist<<<(NE + 255) / 256, 256, 0, stream>>>(deg, ei);
  k_scan<<<1, 1024, 0, stream>>>(deg, rowptr, cursor);
  k_bucket<<<(NE + 255) / 256, 256, 0, stream>>>(ebuf, cursor, ei, ea);
  k_sortseg<<<(NN + 255) / 256, 256, 0, stream>>>(ebuf, rowptr);
  k_ecomb<<<NL * 10, 256, 0, stream>>>(ecomb, ee1, ee2);
  for (int l = 0; l < NL; ++l) {
    k_wt<<<dim3(512 / 32, 256 / 32), 256, 0, stream>>>(
        W1 + (size_t)l * 256 * 512, w1t + (size_t)l * 512 * 256, 256, 512);
    k_wt<<<dim3(256 / 32, 512 / 32), 256, 0, stream>>>(
        W2 + (size_t)l * 512 * 256, w2t + (size_t)l * 256 * 512, 512, 256);
  }
  k_embed<<<NN / 4, 256, 0, stream>>>(hh, x, xe1, xe2);

  for (int l = 0; l < NL; ++l) {
    k_gather<<<NN / 4, 256, 0, stream>>>(aggh, hh, rowptr, ebuf,
                                         ecomb + (size_t)l * 10 * EMB);
    k_mfma1<<<dim3(4, NNP / 128), 256, 0, stream>>>(
        aggh, w1t + (size_t)l * 512 * 256, b1 + (size_t)l * 512, hid);
    k_mfma2<<<dim3(2, NNP / 128), 256, 0, stream>>>(
        hid, w2t + (size_t)l * 256 * 512, b2 + (size_t)l * 256, hh2,
        part_s, part_q);
    k_bnfin<<<1, 256, 0, stream>>>(stats, part_s, part_q,
                                   bng + (size_t)l * EMB, bnb + (size_t)l * EMB);
    k_bnapply<<<NN / 4, 256, 0, stream>>>(hh2, stats, hh, (float*)d_out,
                                          l == NL - 1 ? 1 : 0);
  }
}

// Round 12
// 1229.375 us; speedup vs baseline: 7.3280x; 1.4421x over previous
//
#include <hip/hip_runtime.h>

#define NN 100000
#define NNP 100096          // padded to multiple of 128
#define NE 300000
#define EMB 256
#define NL 5
#define NPART (NNP / 128)   // 782 partial rows
#define BN_EPS 1e-5f

typedef __attribute__((ext_vector_type(8))) _Float16 half8;
typedef __attribute__((ext_vector_type(4))) float f32x4;

__device__ __forceinline__ ushort f2h(float f) {
  _Float16 h = (_Float16)f;
  return *(ushort*)&h;
}
__device__ __forceinline__ float h2f(ushort u) {
  _Float16 h = *(_Float16*)&u;
  return (float)h;
}

// direct global->LDS DMA, 16 B per lane (no VGPR round-trip, nothing to spill)
__device__ __forceinline__ void gl2lds16(const ushort* g, ushort* l) {
  __builtin_amdgcn_global_load_lds(
      (const __attribute__((address_space(1))) void*)g,
      (__attribute__((address_space(3))) void*)l, 16, 0, 0);
}

// XOR-swizzled LDS read address: row stride 128 B, chunk ^= (row&7)
__device__ __forceinline__ ushort* lds_at(ushort* base, int row, int bytecol) {
  return (ushort*)((char*)base + row * 128 + (bytecol ^ ((row & 7) << 4)));
}
// C-tile staging: row stride 256 B, same XOR family
__device__ __forceinline__ ushort* lds_ct(ushort* base, int row, int bytecol) {
  return (ushort*)((char*)base + row * 256 + (bytecol ^ ((row & 7) << 4)));
}

// ---------------------------------------------------------------- embed ----
__global__ __launch_bounds__(256) void k_embed(ushort* __restrict__ hh,
    const int* __restrict__ x, const float* __restrict__ xe1,
    const float* __restrict__ xe2) {
  const int wid = threadIdx.x >> 6, lane = threadIdx.x & 63;
  const int row = blockIdx.x * 4 + wid;
  const int c = lane << 2;
  const int x0 = x[row * 2], x1 = x[row * 2 + 1];
  float4 a = *(const float4*)(xe1 + (size_t)x0 * EMB + c);
  float4 b = *(const float4*)(xe2 + (size_t)x1 * EMB + c);
  ushort4 o;
  o.x = f2h(a.x + b.x); o.y = f2h(a.y + b.y);
  o.z = f2h(a.z + b.z); o.w = f2h(a.w + b.w);
  *(ushort4*)(hh + (size_t)row * EMB + c) = o;
}

// -------------------------------------------------------------- CSR build --
__global__ __launch_bounds__(256) void k_hist(int* __restrict__ deg,
    const int* __restrict__ ei) {
  int e = blockIdx.x * 256 + threadIdx.x;
  if (e < NE) atomicAdd(&deg[ei[NE + e]], 1);
}

__global__ __launch_bounds__(1024) void k_scan(const int* __restrict__ deg,
    int* __restrict__ rowptr, int* __restrict__ cursor) {
  __shared__ int wsum[16], woff[17];
  const int t = threadIdx.x;
  const int lane = t & 63, w = t >> 6;
  int base = 0;
  for (int start = 0; start < NN; start += 1024) {
    const int i = start + t;
    const int v0 = (i < NN) ? deg[i] : 0;
    int v = v0;
#pragma unroll
    for (int off = 1; off < 64; off <<= 1) {
      int x = __shfl_up(v, off);
      if (lane >= off) v += x;
    }
    if (lane == 63) wsum[w] = v;
    __syncthreads();
    if (t == 0) {
      int s = 0;
#pragma unroll
      for (int k = 0; k < 16; ++k) { woff[k] = s; s += wsum[k]; }
      woff[16] = s;
    }
    __syncthreads();
    if (i < NN) {
      int excl = base + woff[w] + v - v0;
      rowptr[i] = excl;
      cursor[i] = excl;
    }
    base += woff[16];
    __syncthreads();
  }
  if (t == 0) rowptr[NN] = base;
}

__global__ __launch_bounds__(256) void k_bucket(int* __restrict__ ebuf,
    int* __restrict__ cursor, const int* __restrict__ ei,
    const int* __restrict__ ea) {
  int e = blockIdx.x * 256 + threadIdx.x;
  if (e >= NE) return;
  int src = ei[e], dst = ei[NE + e];
  int c9 = ea[e * 2] * 3 + ea[e * 2 + 1];
  int pos = atomicAdd(&cursor[dst], 1);
  ebuf[pos] = src | (c9 << 20);
}

// canonical per-node order -> bit-deterministic gather summation
__global__ __launch_bounds__(256) void k_sortseg(int* __restrict__ ebuf,
    const int* __restrict__ rowptr) {
  int i = blockIdx.x * 256 + threadIdx.x;
  if (i >= NN) return;
  const int beg = rowptr[i], end = rowptr[i + 1];
  for (int a = beg + 1; a < end; ++a) {
    int v = ebuf[a];
    int b = a - 1;
    while (b >= beg && ebuf[b] > v) { ebuf[b + 1] = ebuf[b]; --b; }
    ebuf[b + 1] = v;
  }
}

// ecomb[l][k][c]: k<9 -> e1[k/3]+e2[k%3]; k==9 -> self-loop e1[4]+e2[0]
__global__ __launch_bounds__(256) void k_ecomb(float* __restrict__ ecomb,
    const float* __restrict__ ee1, const float* __restrict__ ee2) {
  const int c = threadIdx.x;
  const int l = blockIdx.x / 10, k = blockIdx.x % 10;
  const float* e1l = ee1 + (size_t)l * 5 * EMB;
  const float* e2l = ee2 + (size_t)l * 3 * EMB;
  float v = (k < 9) ? (e1l[(k / 3) * EMB + c] + e2l[(k % 3) * EMB + c])
                    : (e1l[4 * EMB + c] + e2l[c]);
  ecomb[(size_t)blockIdx.x * EMB + c] = v;
}

// ------------------------------------------- weight transpose + fp16 cast --
__global__ __launch_bounds__(256) void k_wt(const float* __restrict__ src,
    ushort* __restrict__ dst, int R, int C) {
  __shared__ float tile[32][33];
  const int t = threadIdx.x;
  const int tr = t >> 5, tc = t & 31;
  const int r0 = blockIdx.y * 32, c0 = blockIdx.x * 32;
#pragma unroll
  for (int i = 0; i < 4; ++i)
    tile[tr + 8 * i][tc] = src[(size_t)(r0 + tr + 8 * i) * C + c0 + tc];
  __syncthreads();
#pragma unroll
  for (int i = 0; i < 4; ++i)
    dst[(size_t)(c0 + tr + 8 * i) * R + r0 + tc] = f2h(tile[tc][tr + 8 * i]);
}

// --------------------------------------------------- gather aggregation ----
__global__ __launch_bounds__(256) void k_gather(ushort* __restrict__ aggh,
    const ushort* __restrict__ hh, const int* __restrict__ rowptr,
    const int* __restrict__ ebuf, const float* __restrict__ ecomb) {
  const int wid = threadIdx.x >> 6, lane = threadIdx.x & 63;
  const int i = blockIdx.x * 4 + wid;
  const int c = lane << 2;
  ushort4 hv = *(const ushort4*)(hh + (size_t)i * EMB + c);
  float4 sv = *(const float4*)(ecomb + 9 * EMB + c);
  float sx = h2f(hv.x) + sv.x, sy = h2f(hv.y) + sv.y;
  float sz = h2f(hv.z) + sv.z, sw = h2f(hv.w) + sv.w;
  const int beg = rowptr[i], end = rowptr[i + 1];
  for (int j = beg; j < end; ++j) {
    int p = ebuf[j];
    int src = p & 0xFFFFF, c9 = p >> 20;
    ushort4 a = *(const ushort4*)(hh + (size_t)src * EMB + c);
    float4 b = *(const float4*)(ecomb + (size_t)c9 * EMB + c);
    sx += h2f(a.x) + b.x; sy += h2f(a.y) + b.y;
    sz += h2f(a.z) + b.z; sw += h2f(a.w) + b.w;
  }
  ushort4 o;
  o.x = f2h(sx); o.y = f2h(sy); o.z = f2h(sz); o.w = f2h(sw);
  *(ushort4*)(aggh + (size_t)i * EMB + c) = o;
}

// ------------------------------------------------------- MFMA fp16 GEMMs ---
// 128x128 tile, BK=64, 4 waves (2x2). Staging: global_load_lds DMA, LDS dest
// linear, global source pre-swizzled (chunk ^= row&7) so swizzled ds_read
// (lds_at) sees logical layout. No staging VGPRs -> no spills.

// GEMM1: C[NNP][512] = relu(A[NNP][256] @ W1 + b1)
__global__ __launch_bounds__(256) void k_mfma1(
    const ushort* __restrict__ A, const ushort* __restrict__ BT,
    const float* __restrict__ bias, ushort* __restrict__ C) {
  __shared__ ushort smem[16384];           // As | Bs, reused as 128x128 C-tile
  ushort* As = smem;                       // [128][64] fp16, 16 KB
  ushort* Bs = smem + 8192;
  const int t = threadIdx.x;
  const int lane = t & 63, w = t >> 6;
  const int wr = w >> 1, wc = w & 1;
  const int m0 = blockIdx.y * 128, n0 = blockIdx.x * 128;
  const int fm = lane & 15, g = lane >> 4;
  const int r_loc = lane >> 3, gchunk = (lane & 7) ^ r_loc;  // source swizzle
  f32x4 acc[4][4];
#pragma unroll
  for (int i = 0; i < 4; ++i)
#pragma unroll
    for (int j = 0; j < 4; ++j) acc[i][j] = (f32x4){0.f, 0.f, 0.f, 0.f};

  for (int k0 = 0; k0 < 256; k0 += 64) {
#pragma unroll
    for (int i = 0; i < 4; ++i) {
      const int seg = w * 4 + i;           // 8 rows per segment
      const int row = 8 * seg + r_loc;
      gl2lds16(A + (size_t)(m0 + row) * 256 + k0 + gchunk * 8, As + seg * 512);
      gl2lds16(BT + (size_t)(n0 + row) * 256 + k0 + gchunk * 8, Bs + seg * 512);
    }
    __syncthreads();                        // drains vmcnt -> LDS ready
#pragma unroll
    for (int kk = 0; kk < 2; ++kk) {
      half8 af[4], bf[4];
#pragma unroll
      for (int mi = 0; mi < 4; ++mi)
        af[mi] = *(const half8*)lds_at(As, wr * 64 + mi * 16 + fm,
                                       kk * 64 + g * 16);
#pragma unroll
      for (int ni = 0; ni < 4; ++ni)
        bf[ni] = *(const half8*)lds_at(Bs, wc * 64 + ni * 16 + fm,
                                       kk * 64 + g * 16);
#pragma unroll
      for (int mi = 0; mi < 4; ++mi)
#pragma unroll
        for (int ni = 0; ni < 4; ++ni)
          acc[mi][ni] = __builtin_amdgcn_mfma_f32_16x16x32_f16(
              bf[ni], af[mi], acc[mi][ni], 0, 0, 0);
    }
    __syncthreads();                        // compute done before next stage
  }
  // ---- stage C tile (bias+relu+fp16) into LDS ----
#pragma unroll
  for (int ni = 0; ni < 4; ++ni) {
    const int col = wc * 64 + ni * 16 + g * 4;
    const float4 b4 = *(const float4*)(bias + n0 + col);
#pragma unroll
    for (int mi = 0; mi < 4; ++mi) {
      const int row = wr * 64 + mi * 16 + fm;
      ushort4 o;
      o.x = f2h(fmaxf(acc[mi][ni].x + b4.x, 0.f));
      o.y = f2h(fmaxf(acc[mi][ni].y + b4.y, 0.f));
      o.z = f2h(fmaxf(acc[mi][ni].z + b4.z, 0.f));
      o.w = f2h(fmaxf(acc[mi][ni].w + b4.w, 0.f));
      *(ushort4*)lds_ct(smem, row, col * 2) = o;
    }
  }
  __syncthreads();
  // ---- coalesced store ----
#pragma unroll
  for (int rr = 0; rr < 2; ++rr) {
    const int row = rr * 64 + (t >> 2);
    const int grow = m0 + row;
    if (grow < NN) {
#pragma unroll
      for (int it = 0; it < 4; ++it) {
        const int bc = it * 64 + (t & 3) * 16;
        uint4 v = *(const uint4*)lds_ct(smem, row, bc);
        *(uint4*)((char*)(C + (size_t)grow * 512 + n0) + bc) = v;
      }
    }
  }
}

// GEMM2: hh2[NNP][256] = A[NNP][512] @ W2 + b2 (fp16 out) + BN partials (fp32)
__global__ __launch_bounds__(256) void k_mfma2(
    const ushort* __restrict__ A, const ushort* __restrict__ BT,
    const float* __restrict__ bias, ushort* __restrict__ hh2,
    float* __restrict__ part_s, float* __restrict__ part_q) {
  __shared__ ushort smem[16384];
  __shared__ float sS[128], sQ[128];
  ushort* As = smem;
  ushort* Bs = smem + 8192;
  const int t = threadIdx.x;
  if (t < 128) { sS[t] = 0.f; sQ[t] = 0.f; }
  const int lane = t & 63, w = t >> 6;
  const int wr = w >> 1, wc = w & 1;
  const int m0 = blockIdx.y * 128, n0 = blockIdx.x * 128;
  const int fm = lane & 15, g = lane >> 4;
  const int r_loc = lane >> 3, gchunk = (lane & 7) ^ r_loc;
  f32x4 acc[4][4];
#pragma unroll
  for (int i = 0; i < 4; ++i)
#pragma unroll
    for (int j = 0; j < 4; ++j) acc[i][j] = (f32x4){0.f, 0.f, 0.f, 0.f};

  for (int k0 = 0; k0 < 512; k0 += 64) {
#pragma unroll
    for (int i = 0; i < 4; ++i) {
      const int seg = w * 4 + i;
      const int row = 8 * seg + r_loc;
      gl2lds16(A + (size_t)(m0 + row) * 512 + k0 + gchunk * 8, As + seg * 512);
      gl2lds16(BT + (size_t)(n0 + row) * 512 + k0 + gchunk * 8, Bs + seg * 512);
    }
    __syncthreads();
#pragma unroll
    for (int kk = 0; kk < 2; ++kk) {
      half8 af[4], bf[4];
#pragma unroll
      for (int mi = 0; mi < 4; ++mi)
        af[mi] = *(const half8*)lds_at(As, wr * 64 + mi * 16 + fm,
                                       kk * 64 + g * 16);
#pragma unroll
      for (int ni = 0; ni < 4; ++ni)
        bf[ni] = *(const half8*)lds_at(Bs, wc * 64 + ni * 16 + fm,
                                       kk * 64 + g * 16);
#pragma unroll
      for (int mi = 0; mi < 4; ++mi)
#pragma unroll
        for (int ni = 0; ni < 4; ++ni)
          acc[mi][ni] = __builtin_amdgcn_mfma_f32_16x16x32_f16(
              bf[ni], af[mi], acc[mi][ni], 0, 0, 0);
    }
    __syncthreads();
  }
  // ---- stats (exact fp32) + stage fp16 C tile ----
#pragma unroll
  for (int ni = 0; ni < 4; ++ni) {
    const int col = wc * 64 + ni * 16 + g * 4;
    const float4 b4 = *(const float4*)(bias + n0 + col);
    float sv[4] = {0.f, 0.f, 0.f, 0.f}, qv[4] = {0.f, 0.f, 0.f, 0.f};
#pragma unroll
    for (int mi = 0; mi < 4; ++mi) {
      const int row = wr * 64 + mi * 16 + fm;
      const float v0 = acc[mi][ni].x + b4.x;
      const float v1 = acc[mi][ni].y + b4.y;
      const float v2 = acc[mi][ni].z + b4.z;
      const float v3 = acc[mi][ni].w + b4.w;
      if (m0 + row < NN) {
        sv[0] += v0; sv[1] += v1; sv[2] += v2; sv[3] += v3;
        qv[0] += v0 * v0; qv[1] += v1 * v1; qv[2] += v2 * v2; qv[3] += v3 * v3;
      }
      ushort4 o;
      o.x = f2h(v0); o.y = f2h(v1); o.z = f2h(v2); o.w = f2h(v3);
      *(ushort4*)lds_ct(smem, row, col * 2) = o;
    }
#pragma unroll
    for (int msk = 1; msk < 16; msk <<= 1) {
#pragma unroll
      for (int j = 0; j < 4; ++j) {
        sv[j] += __shfl_xor(sv[j], msk);
        qv[j] += __shfl_xor(qv[j], msk);
      }
    }
    if (fm == 0) {
#pragma unroll
      for (int j = 0; j < 4; ++j) {
        atomicAdd(&sS[col + j], sv[j]);
        atomicAdd(&sQ[col + j], qv[j]);
      }
    }
  }
  __syncthreads();
  // ---- coalesced fp16 store ----
#pragma unroll
  for (int rr = 0; rr < 2; ++rr) {
    const int row = rr * 64 + (t >> 2);
    const int grow = m0 + row;
    if (grow < NN) {
#pragma unroll
      for (int it = 0; it < 4; ++it) {
        const int bc = it * 64 + (t & 3) * 16;
        uint4 v = *(const uint4*)lds_ct(smem, row, bc);
        *(uint4*)((char*)(hh2 + (size_t)grow * 256 + n0) + bc) = v;
      }
    }
  }
  if (t < 128) {
    part_s[(size_t)blockIdx.y * 256 + n0 + t] = sS[t];
    part_q[(size_t)blockIdx.y * 256 + n0 + t] = sQ[t];
  }
}

// -------------------------------------------------------------- BN pieces --
// one block per channel: parallel deterministic tree reduction of partials
__global__ __launch_bounds__(128) void k_bnfin(float* __restrict__ stats,
    const float* __restrict__ part_s, const float* __restrict__ part_q,
    const float* __restrict__ g, const float* __restrict__ b) {
  const int c = blockIdx.x;        // 256 blocks
  const int t = threadIdx.x;       // 128 threads = 2 waves
  __shared__ float red[4];
  float s = 0.f, q = 0.f;
  for (int r = t; r < NPART; r += 128) {
    s += part_s[(size_t)r * 256 + c];
    q += part_q[(size_t)r * 256 + c];
  }
#pragma unroll
  for (int m = 1; m < 64; m <<= 1) {
    s += __shfl_xor(s, m);
    q += __shfl_xor(q, m);
  }
  if ((t & 63) == 0) { red[(t >> 6) * 2] = s; red[(t >> 6) * 2 + 1] = q; }
  __syncthreads();
  if (t == 0) {
    float st = red[0] + red[2];
    float qt = red[1] + red[3];
    float mean = st * (1.0f / NN);
    float var = qt * (1.0f / NN) - mean * mean;
    float A = g[c] * rsqrtf(var + BN_EPS);
    stats[c] = A;
    stats[256 + c] = b[c] - mean * A;
  }
}

// mode 0: relu -> hh fp16 (next layer); mode 1: final -> hout fp32, no relu
__global__ __launch_bounds__(256) void k_bnapply(
    const ushort* __restrict__ hh2, const float* __restrict__ stats,
    ushort* __restrict__ hh, float* __restrict__ hout, int mode) {
  const int wid = threadIdx.x >> 6, lane = threadIdx.x & 63;
  const int row = blockIdx.x * 4 + wid;
  const int c = lane << 2;
  ushort4 v4 = *(const ushort4*)(hh2 + (size_t)row * EMB + c);
  float4 Av = *(const float4*)(stats + c);
  float4 Bv = *(const float4*)(stats + 256 + c);
  float o0 = fmaf(h2f(v4.x), Av.x, Bv.x);
  float o1 = fmaf(h2f(v4.y), Av.y, Bv.y);
  float o2 = fmaf(h2f(v4.z), Av.z, Bv.z);
  float o3 = fmaf(h2f(v4.w), Av.w, Bv.w);
  if (mode == 0) {
    ushort4 o;
    o.x = f2h(fmaxf(o0, 0.f)); o.y = f2h(fmaxf(o1, 0.f));
    o.z = f2h(fmaxf(o2, 0.f)); o.w = f2h(fmaxf(o3, 0.f));
    *(ushort4*)(hh + (size_t)row * EMB + c) = o;
  } else {
    *(float4*)(hout + (size_t)row * EMB + c) = make_float4(o0, o1, o2, o3);
  }
}

// ------------------------------------------------------------------ host ---
extern "C" void kernel_launch(void* const* d_in, const int* in_sizes, int n_in,
                              void* d_out, int out_size, void* d_ws, size_t ws_size,
                              hipStream_t stream) {
  const int* x    = (const int*)d_in[0];
  const int* ei   = (const int*)d_in[1];
  const int* ea   = (const int*)d_in[2];
  const float* xe1 = (const float*)d_in[3];
  const float* xe2 = (const float*)d_in[4];
  const float* ee1 = (const float*)d_in[5];
  const float* ee2 = (const float*)d_in[6];
  const float* W1  = (const float*)d_in[7];   // [L][256][512]
  const float* b1  = (const float*)d_in[8];   // [L][512]
  const float* W2  = (const float*)d_in[9];   // [L][512][256]
  const float* b2  = (const float*)d_in[10];  // [L][256]
  const float* bng = (const float*)d_in[11];
  const float* bnb = (const float*)d_in[12];

  char* ws = (char*)d_ws;
  size_t off = 0;
  ushort* aggh = (ushort*)(ws + off); off += (size_t)NNP * 256 * 2;
  ushort* hh2  = (ushort*)(ws + off); off += (size_t)NNP * 256 * 2;
  ushort* hid  = (ushort*)(ws + off); off += (size_t)NNP * 512 * 2;
  ushort* hh   = (ushort*)(ws + off); off += (size_t)NNP * 256 * 2;
  ushort* w1t  = (ushort*)(ws + off); off += (size_t)NL * 512 * 256 * 2;
  ushort* w2t  = (ushort*)(ws + off); off += (size_t)NL * 256 * 512 * 2;
  float* ecomb = (float*)(ws + off); off += (size_t)NL * 10 * EMB * 4;
  float* stats = (float*)(ws + off); off += 512 * 4;
  float* part_s = (float*)(ws + off); off += (size_t)NPART * 256 * 4;
  float* part_q = (float*)(ws + off); off += (size_t)NPART * 256 * 4;
  int* rowptr = (int*)(ws + off); off += (size_t)(NN + 1) * 4;
  int* cursor = (int*)(ws + off); off += (size_t)NN * 4;
  int* ebuf   = (int*)(ws + off); off += (size_t)NE * 4;
  int* deg = ebuf;   // alias: deg dead before ebuf written

  // one-time prep
  hipMemsetAsync(deg, 0, NN * sizeof(int), stream);
  k_hist<<<(NE + 255) / 256, 256, 0, stream>>>(deg, ei);
  k_scan<<<1, 1024, 0, stream>>>(deg, rowptr, cursor);
  k_bucket<<<(NE + 255) / 256, 256, 0, stream>>>(ebuf, cursor, ei, ea);
  k_sortseg<<<(NN + 255) / 256, 256, 0, stream>>>(ebuf, rowptr);
  k_ecomb<<<NL * 10, 256, 0, stream>>>(ecomb, ee1, ee2);
  for (int l = 0; l < NL; ++l) {
    k_wt<<<dim3(512 / 32, 256 / 32), 256, 0, stream>>>(
        W1 + (size_t)l * 256 * 512, w1t + (size_t)l * 512 * 256, 256, 512);
    k_wt<<<dim3(256 / 32, 512 / 32), 256, 0, stream>>>(
        W2 + (size_t)l * 512 * 256, w2t + (size_t)l * 256 * 512, 512, 256);
  }
  k_embed<<<NN / 4, 256, 0, stream>>>(hh, x, xe1, xe2);

  for (int l = 0; l < NL; ++l) {
    k_gather<<<NN / 4, 256, 0, stream>>>(aggh, hh, rowptr, ebuf,
                                         ecomb + (size_t)l * 10 * EMB);
    k_mfma1<<<dim3(4, NNP / 128), 256, 0, stream>>>(
        aggh, w1t + (size_t)l * 512 * 256, b1 + (size_t)l * 512, hid);
    k_mfma2<<<dim3(2, NNP / 128), 256, 0, stream>>>(
        hid, w2t + (size_t)l * 256 * 512, b2 + (size_t)l * 256, hh2,
        part_s, part_q);
    k_bnfin<<<256, 128, 0, stream>>>(stats, part_s, part_q,
                                     bng + (size_t)l * EMB, bnb + (size_t)l * EMB);
    k_bnapply<<<NN / 4, 256, 0, stream>>>(hh2, stats, hh, (float*)d_out,
                                          l == NL - 1 ? 1 : 0);
  }
}

// Round 13
// 1068.894 us; speedup vs baseline: 8.4283x; 1.1501x over previous
//
#include <hip/hip_runtime.h>

#define NN 100000
#define NNP 100096          // padded to multiple of 128
#define NE 300000
#define EMB 256
#define NL 5
#define NPART (NNP / 128)   // 782 partial rows
#define NBLK 98             // ceil(NN/1024) scan blocks
#define BN_EPS 1e-5f

typedef __attribute__((ext_vector_type(8))) _Float16 half8;
typedef __attribute__((ext_vector_type(4))) float f32x4;

__device__ __forceinline__ ushort f2h(float f) {
  _Float16 h = (_Float16)f;
  return *(ushort*)&h;
}
__device__ __forceinline__ float h2f(ushort u) {
  _Float16 h = *(_Float16*)&u;
  return (float)h;
}

// direct global->LDS DMA, 16 B per lane (no VGPR round-trip, nothing to spill)
__device__ __forceinline__ void gl2lds16(const ushort* g, ushort* l) {
  __builtin_amdgcn_global_load_lds(
      (const __attribute__((address_space(1))) void*)g,
      (__attribute__((address_space(3))) void*)l, 16, 0, 0);
}

// XOR-swizzled LDS read address: row stride 128 B, chunk ^= (row&7)
__device__ __forceinline__ ushort* lds_at(ushort* base, int row, int bytecol) {
  return (ushort*)((char*)base + row * 128 + (bytecol ^ ((row & 7) << 4)));
}
// C-tile staging: row stride 256 B, same XOR family
__device__ __forceinline__ ushort* lds_ct(ushort* base, int row, int bytecol) {
  return (ushort*)((char*)base + row * 256 + (bytecol ^ ((row & 7) << 4)));
}

// ---------------------------------------------------------------- embed ----
__global__ __launch_bounds__(256) void k_embed(ushort* __restrict__ hh,
    const int* __restrict__ x, const float* __restrict__ xe1,
    const float* __restrict__ xe2) {
  const int wid = threadIdx.x >> 6, lane = threadIdx.x & 63;
  const int row = blockIdx.x * 4 + wid;
  const int c = lane << 2;
  const int x0 = x[row * 2], x1 = x[row * 2 + 1];
  float4 a = *(const float4*)(xe1 + (size_t)x0 * EMB + c);
  float4 b = *(const float4*)(xe2 + (size_t)x1 * EMB + c);
  ushort4 o;
  o.x = f2h(a.x + b.x); o.y = f2h(a.y + b.y);
  o.z = f2h(a.z + b.z); o.w = f2h(a.w + b.w);
  *(ushort4*)(hh + (size_t)row * EMB + c) = o;
}

// -------------------------------------------------------------- CSR build --
__global__ __launch_bounds__(256) void k_hist(int* __restrict__ deg,
    const int* __restrict__ ei) {
  int e = blockIdx.x * 256 + threadIdx.x;
  if (e < NE) atomicAdd(&deg[ei[NE + e]], 1);
}

// phase A: per-1024-chunk totals
__global__ __launch_bounds__(256) void k_scan_a(const int* __restrict__ deg,
    int* __restrict__ bsum) {
  const int t = threadIdx.x, blk = blockIdx.x;
  const int base = blk * 1024 + t * 4;
  int s = 0;
#pragma unroll
  for (int j = 0; j < 4; ++j) {
    int i = base + j;
    if (i < NN) s += deg[i];
  }
  __shared__ int ws[4];
#pragma unroll
  for (int m = 1; m < 64; m <<= 1) s += __shfl_xor(s, m);
  if ((t & 63) == 0) ws[t >> 6] = s;
  __syncthreads();
  if (t == 0) bsum[blk] = ws[0] + ws[1] + ws[2] + ws[3];
}

// phase B: exclusive scan of the 98 block sums (1 block, 128 thr)
__global__ __launch_bounds__(128) void k_scan_b(const int* __restrict__ bsum,
    int* __restrict__ boff, int* __restrict__ rowptr) {
  const int t = threadIdx.x;
  const int lane = t & 63, w = t >> 6;
  __shared__ int wtot[2];
  int v = (t < NBLK) ? bsum[t] : 0;
  int inc = v;
#pragma unroll
  for (int off = 1; off < 64; off <<= 1) {
    int x = __shfl_up(inc, off);
    if (lane >= off) inc += x;
  }
  if (lane == 63) wtot[w] = inc;
  __syncthreads();
  int add = (w == 1) ? wtot[0] : 0;
  if (t < NBLK) boff[t] = inc - v + add;
  if (t == 0) rowptr[NN] = wtot[0] + wtot[1];
}

// phase C: intra-chunk exclusive scan + block offset -> rowptr, cursor
__global__ __launch_bounds__(256) void k_scan_c(const int* __restrict__ deg,
    const int* __restrict__ boff, int* __restrict__ rowptr,
    int* __restrict__ cursor) {
  const int t = threadIdx.x, blk = blockIdx.x;
  const int lane = t & 63, w = t >> 6;
  const int base = blk * 1024 + t * 4;
  int v[4];
  int s = 0;
#pragma unroll
  for (int j = 0; j < 4; ++j) {
    int i = base + j;
    v[j] = (i < NN) ? deg[i] : 0;
    s += v[j];
  }
  int inc = s;
#pragma unroll
  for (int off = 1; off < 64; off <<= 1) {
    int x = __shfl_up(inc, off);
    if (lane >= off) inc += x;
  }
  __shared__ int wsum[4];
  if (lane == 63) wsum[w] = inc;
  __syncthreads();
  int wadd = 0;
#pragma unroll
  for (int k = 0; k < 4; ++k)
    if (k < w) wadd += wsum[k];
  int excl = boff[blk] + wadd + inc - s;
#pragma unroll
  for (int j = 0; j < 4; ++j) {
    int i = base + j;
    if (i < NN) { rowptr[i] = excl; cursor[i] = excl; }
    excl += v[j];
  }
}

__global__ __launch_bounds__(256) void k_bucket(int* __restrict__ ebuf,
    int* __restrict__ cursor, const int* __restrict__ ei,
    const int* __restrict__ ea) {
  int e = blockIdx.x * 256 + threadIdx.x;
  if (e >= NE) return;
  int src = ei[e], dst = ei[NE + e];
  int c9 = ea[e * 2] * 3 + ea[e * 2 + 1];
  int pos = atomicAdd(&cursor[dst], 1);
  ebuf[pos] = src | (c9 << 20);
}

// canonical per-node order -> bit-deterministic gather summation
__global__ __launch_bounds__(256) void k_sortseg(int* __restrict__ ebuf,
    const int* __restrict__ rowptr) {
  int i = blockIdx.x * 256 + threadIdx.x;
  if (i >= NN) return;
  const int beg = rowptr[i], end = rowptr[i + 1];
  for (int a = beg + 1; a < end; ++a) {
    int v = ebuf[a];
    int b = a - 1;
    while (b >= beg && ebuf[b] > v) { ebuf[b + 1] = ebuf[b]; --b; }
    ebuf[b + 1] = v;
  }
}

// ecomb[l][k][c]: k<9 -> e1[k/3]+e2[k%3]; k==9 -> self-loop e1[4]+e2[0]
__global__ __launch_bounds__(256) void k_ecomb(float* __restrict__ ecomb,
    const float* __restrict__ ee1, const float* __restrict__ ee2) {
  const int c = threadIdx.x;
  const int l = blockIdx.x / 10, k = blockIdx.x % 10;
  const float* e1l = ee1 + (size_t)l * 5 * EMB;
  const float* e2l = ee2 + (size_t)l * 3 * EMB;
  float v = (k < 9) ? (e1l[(k / 3) * EMB + c] + e2l[(k % 3) * EMB + c])
                    : (e1l[4 * EMB + c] + e2l[c]);
  ecomb[(size_t)blockIdx.x * EMB + c] = v;
}

// ------------------------------------------- weight transpose + fp16 cast --
__global__ __launch_bounds__(256) void k_wt(const float* __restrict__ src,
    ushort* __restrict__ dst, int R, int C) {
  __shared__ float tile[32][33];
  const int t = threadIdx.x;
  const int tr = t >> 5, tc = t & 31;
  const int r0 = blockIdx.y * 32, c0 = blockIdx.x * 32;
#pragma unroll
  for (int i = 0; i < 4; ++i)
    tile[tr + 8 * i][tc] = src[(size_t)(r0 + tr + 8 * i) * C + c0 + tc];
  __syncthreads();
#pragma unroll
  for (int i = 0; i < 4; ++i)
    dst[(size_t)(c0 + tr + 8 * i) * R + r0 + tc] = f2h(tile[tc][tr + 8 * i]);
}

// --------------------------------------------------- gather aggregation ----
// fuse=0: src_h holds ready h (layer 0, embed output)
// fuse=1: src_h holds pre-BN h2; apply relu(A*v+B) from stats inline
__global__ __launch_bounds__(256) void k_gather(ushort* __restrict__ aggh,
    const ushort* __restrict__ src_h, const int* __restrict__ rowptr,
    const int* __restrict__ ebuf, const float* __restrict__ ecomb,
    const float* __restrict__ stats, int fuse) {
  const int wid = threadIdx.x >> 6, lane = threadIdx.x & 63;
  const int i = blockIdx.x * 4 + wid;
  const int c = lane << 2;
  float4 Av = make_float4(1.f, 1.f, 1.f, 1.f);
  float4 Bv = make_float4(0.f, 0.f, 0.f, 0.f);
  if (fuse) {
    Av = *(const float4*)(stats + c);
    Bv = *(const float4*)(stats + 256 + c);
  }
  ushort4 hv = *(const ushort4*)(src_h + (size_t)i * EMB + c);
  float4 sv = *(const float4*)(ecomb + 9 * EMB + c);
  float hx = h2f(hv.x), hy = h2f(hv.y), hz = h2f(hv.z), hw = h2f(hv.w);
  if (fuse) {
    hx = fmaxf(fmaf(hx, Av.x, Bv.x), 0.f);
    hy = fmaxf(fmaf(hy, Av.y, Bv.y), 0.f);
    hz = fmaxf(fmaf(hz, Av.z, Bv.z), 0.f);
    hw = fmaxf(fmaf(hw, Av.w, Bv.w), 0.f);
  }
  float sx = hx + sv.x, sy = hy + sv.y, sz = hz + sv.z, sw = hw + sv.w;
  const int beg = rowptr[i], end = rowptr[i + 1];
  for (int j = beg; j < end; ++j) {
    int p = ebuf[j];
    int src = p & 0xFFFFF, c9 = p >> 20;
    ushort4 a = *(const ushort4*)(src_h + (size_t)src * EMB + c);
    float4 b = *(const float4*)(ecomb + (size_t)c9 * EMB + c);
    float ax = h2f(a.x), ay = h2f(a.y), az = h2f(a.z), aw = h2f(a.w);
    if (fuse) {
      ax = fmaxf(fmaf(ax, Av.x, Bv.x), 0.f);
      ay = fmaxf(fmaf(ay, Av.y, Bv.y), 0.f);
      az = fmaxf(fmaf(az, Av.z, Bv.z), 0.f);
      aw = fmaxf(fmaf(aw, Av.w, Bv.w), 0.f);
    }
    sx += ax + b.x; sy += ay + b.y; sz += az + b.z; sw += aw + b.w;
  }
  ushort4 o;
  o.x = f2h(sx); o.y = f2h(sy); o.z = f2h(sz); o.w = f2h(sw);
  *(ushort4*)(aggh + (size_t)i * EMB + c) = o;
}

// ------------------------------------------------------- MFMA fp16 GEMMs ---
// 128x128 tile, BK=64, 4 waves (2x2). Staging: global_load_lds DMA, LDS dest
// linear, global source pre-swizzled (chunk ^= row&7) so swizzled ds_read
// (lds_at) sees logical layout. No staging VGPRs -> no spills.

// GEMM1: C[NNP][512] = relu(A[NNP][256] @ W1 + b1)
__global__ __launch_bounds__(256) void k_mfma1(
    const ushort* __restrict__ A, const ushort* __restrict__ BT,
    const float* __restrict__ bias, ushort* __restrict__ C) {
  __shared__ ushort smem[16384];           // As | Bs, reused as 128x128 C-tile
  ushort* As = smem;                       // [128][64] fp16, 16 KB
  ushort* Bs = smem + 8192;
  const int t = threadIdx.x;
  const int lane = t & 63, w = t >> 6;
  const int wr = w >> 1, wc = w & 1;
  const int m0 = blockIdx.y * 128, n0 = blockIdx.x * 128;
  const int fm = lane & 15, g = lane >> 4;
  const int r_loc = lane >> 3, gchunk = (lane & 7) ^ r_loc;  // source swizzle
  f32x4 acc[4][4];
#pragma unroll
  for (int i = 0; i < 4; ++i)
#pragma unroll
    for (int j = 0; j < 4; ++j) acc[i][j] = (f32x4){0.f, 0.f, 0.f, 0.f};

  for (int k0 = 0; k0 < 256; k0 += 64) {
#pragma unroll
    for (int i = 0; i < 4; ++i) {
      const int seg = w * 4 + i;           // 8 rows per segment
      const int row = 8 * seg + r_loc;
      gl2lds16(A + (size_t)(m0 + row) * 256 + k0 + gchunk * 8, As + seg * 512);
      gl2lds16(BT + (size_t)(n0 + row) * 256 + k0 + gchunk * 8, Bs + seg * 512);
    }
    __syncthreads();                        // drains vmcnt -> LDS ready
#pragma unroll
    for (int kk = 0; kk < 2; ++kk) {
      half8 af[4], bf[4];
#pragma unroll
      for (int mi = 0; mi < 4; ++mi)
        af[mi] = *(const half8*)lds_at(As, wr * 64 + mi * 16 + fm,
                                       kk * 64 + g * 16);
#pragma unroll
      for (int ni = 0; ni < 4; ++ni)
        bf[ni] = *(const half8*)lds_at(Bs, wc * 64 + ni * 16 + fm,
                                       kk * 64 + g * 16);
#pragma unroll
      for (int mi = 0; mi < 4; ++mi)
#pragma unroll
        for (int ni = 0; ni < 4; ++ni)
          acc[mi][ni] = __builtin_amdgcn_mfma_f32_16x16x32_f16(
              bf[ni], af[mi], acc[mi][ni], 0, 0, 0);
    }
    __syncthreads();                        // compute done before next stage
  }
  // ---- stage C tile (bias+relu+fp16) into LDS ----
#pragma unroll
  for (int ni = 0; ni < 4; ++ni) {
    const int col = wc * 64 + ni * 16 + g * 4;
    const float4 b4 = *(const float4*)(bias + n0 + col);
#pragma unroll
    for (int mi = 0; mi < 4; ++mi) {
      const int row = wr * 64 + mi * 16 + fm;
      ushort4 o;
      o.x = f2h(fmaxf(acc[mi][ni].x + b4.x, 0.f));
      o.y = f2h(fmaxf(acc[mi][ni].y + b4.y, 0.f));
      o.z = f2h(fmaxf(acc[mi][ni].z + b4.z, 0.f));
      o.w = f2h(fmaxf(acc[mi][ni].w + b4.w, 0.f));
      *(ushort4*)lds_ct(smem, row, col * 2) = o;
    }
  }
  __syncthreads();
  // ---- coalesced store ----
#pragma unroll
  for (int rr = 0; rr < 2; ++rr) {
    const int row = rr * 64 + (t >> 2);
    const int grow = m0 + row;
    if (grow < NN) {
#pragma unroll
      for (int it = 0; it < 4; ++it) {
        const int bc = it * 64 + (t & 3) * 16;
        uint4 v = *(const uint4*)lds_ct(smem, row, bc);
        *(uint4*)((char*)(C + (size_t)grow * 512 + n0) + bc) = v;
      }
    }
  }
}

// GEMM2: hh2[NNP][256] = A[NNP][512] @ W2 + b2 (fp16 out) + BN partials (fp32)
__global__ __launch_bounds__(256) void k_mfma2(
    const ushort* __restrict__ A, const ushort* __restrict__ BT,
    const float* __restrict__ bias, ushort* __restrict__ hh2,
    float* __restrict__ part_s, float* __restrict__ part_q) {
  __shared__ ushort smem[16384];
  __shared__ float sS[128], sQ[128];
  ushort* As = smem;
  ushort* Bs = smem + 8192;
  const int t = threadIdx.x;
  if (t < 128) { sS[t] = 0.f; sQ[t] = 0.f; }
  const int lane = t & 63, w = t >> 6;
  const int wr = w >> 1, wc = w & 1;
  const int m0 = blockIdx.y * 128, n0 = blockIdx.x * 128;
  const int fm = lane & 15, g = lane >> 4;
  const int r_loc = lane >> 3, gchunk = (lane & 7) ^ r_loc;
  f32x4 acc[4][4];
#pragma unroll
  for (int i = 0; i < 4; ++i)
#pragma unroll
    for (int j = 0; j < 4; ++j) acc[i][j] = (f32x4){0.f, 0.f, 0.f, 0.f};

  for (int k0 = 0; k0 < 512; k0 += 64) {
#pragma unroll
    for (int i = 0; i < 4; ++i) {
      const int seg = w * 4 + i;
      const int row = 8 * seg + r_loc;
      gl2lds16(A + (size_t)(m0 + row) * 512 + k0 + gchunk * 8, As + seg * 512);
      gl2lds16(BT + (size_t)(n0 + row) * 512 + k0 + gchunk * 8, Bs + seg * 512);
    }
    __syncthreads();
#pragma unroll
    for (int kk = 0; kk < 2; ++kk) {
      half8 af[4], bf[4];
#pragma unroll
      for (int mi = 0; mi < 4; ++mi)
        af[mi] = *(const half8*)lds_at(As, wr * 64 + mi * 16 + fm,
                                       kk * 64 + g * 16);
#pragma unroll
      for (int ni = 0; ni < 4; ++ni)
        bf[ni] = *(const half8*)lds_at(Bs, wc * 64 + ni * 16 + fm,
                                       kk * 64 + g * 16);
#pragma unroll
      for (int mi = 0; mi < 4; ++mi)
#pragma unroll
        for (int ni = 0; ni < 4; ++ni)
          acc[mi][ni] = __builtin_amdgcn_mfma_f32_16x16x32_f16(
              bf[ni], af[mi], acc[mi][ni], 0, 0, 0);
    }
    __syncthreads();
  }
  // ---- stats (exact fp32) + stage fp16 C tile ----
#pragma unroll
  for (int ni = 0; ni < 4; ++ni) {
    const int col = wc * 64 + ni * 16 + g * 4;
    const float4 b4 = *(const float4*)(bias + n0 + col);
    float sv[4] = {0.f, 0.f, 0.f, 0.f}, qv[4] = {0.f, 0.f, 0.f, 0.f};
#pragma unroll
    for (int mi = 0; mi < 4; ++mi) {
      const int row = wr * 64 + mi * 16 + fm;
      const float v0 = acc[mi][ni].x + b4.x;
      const float v1 = acc[mi][ni].y + b4.y;
      const float v2 = acc[mi][ni].z + b4.z;
      const float v3 = acc[mi][ni].w + b4.w;
      if (m0 + row < NN) {
        sv[0] += v0; sv[1] += v1; sv[2] += v2; sv[3] += v3;
        qv[0] += v0 * v0; qv[1] += v1 * v1; qv[2] += v2 * v2; qv[3] += v3 * v3;
      }
      ushort4 o;
      o.x = f2h(v0); o.y = f2h(v1); o.z = f2h(v2); o.w = f2h(v3);
      *(ushort4*)lds_ct(smem, row, col * 2) = o;
    }
#pragma unroll
    for (int msk = 1; msk < 16; msk <<= 1) {
#pragma unroll
      for (int j = 0; j < 4; ++j) {
        sv[j] += __shfl_xor(sv[j], msk);
        qv[j] += __shfl_xor(qv[j], msk);
      }
    }
    if (fm == 0) {
#pragma unroll
      for (int j = 0; j < 4; ++j) {
        atomicAdd(&sS[col + j], sv[j]);
        atomicAdd(&sQ[col + j], qv[j]);
      }
    }
  }
  __syncthreads();
  // ---- coalesced fp16 store ----
#pragma unroll
  for (int rr = 0; rr < 2; ++rr) {
    const int row = rr * 64 + (t >> 2);
    const int grow = m0 + row;
    if (grow < NN) {
#pragma unroll
      for (int it = 0; it < 4; ++it) {
        const int bc = it * 64 + (t & 3) * 16;
        uint4 v = *(const uint4*)lds_ct(smem, row, bc);
        *(uint4*)((char*)(hh2 + (size_t)grow * 256 + n0) + bc) = v;
      }
    }
  }
  if (t < 128) {
    part_s[(size_t)blockIdx.y * 256 + n0 + t] = sS[t];
    part_q[(size_t)blockIdx.y * 256 + n0 + t] = sQ[t];
  }
}

// -------------------------------------------------------------- BN pieces --
// one block per channel: parallel deterministic tree reduction of partials
__global__ __launch_bounds__(128) void k_bnfin(float* __restrict__ stats,
    const float* __restrict__ part_s, const float* __restrict__ part_q,
    const float* __restrict__ g, const float* __restrict__ b) {
  const int c = blockIdx.x;        // 256 blocks
  const int t = threadIdx.x;       // 128 threads = 2 waves
  __shared__ float red[4];
  float s = 0.f, q = 0.f;
  for (int r = t; r < NPART; r += 128) {
    s += part_s[(size_t)r * 256 + c];
    q += part_q[(size_t)r * 256 + c];
  }
#pragma unroll
  for (int m = 1; m < 64; m <<= 1) {
    s += __shfl_xor(s, m);
    q += __shfl_xor(q, m);
  }
  if ((t & 63) == 0) { red[(t >> 6) * 2] = s; red[(t >> 6) * 2 + 1] = q; }
  __syncthreads();
  if (t == 0) {
    float st = red[0] + red[2];
    float qt = red[1] + red[3];
    float mean = st * (1.0f / NN);
    float var = qt * (1.0f / NN) - mean * mean;
    float A = g[c] * rsqrtf(var + BN_EPS);
    stats[c] = A;
    stats[256 + c] = b[c] - mean * A;
  }
}

// final layer only: BN (no relu) -> fp32 d_out
__global__ __launch_bounds__(256) void k_bnapply(
    const ushort* __restrict__ hh2, const float* __restrict__ stats,
    float* __restrict__ hout) {
  const int wid = threadIdx.x >> 6, lane = threadIdx.x & 63;
  const int row = blockIdx.x * 4 + wid;
  const int c = lane << 2;
  ushort4 v4 = *(const ushort4*)(hh2 + (size_t)row * EMB + c);
  float4 Av = *(const float4*)(stats + c);
  float4 Bv = *(const float4*)(stats + 256 + c);
  float4 o;
  o.x = fmaf(h2f(v4.x), Av.x, Bv.x);
  o.y = fmaf(h2f(v4.y), Av.y, Bv.y);
  o.z = fmaf(h2f(v4.z), Av.z, Bv.z);
  o.w = fmaf(h2f(v4.w), Av.w, Bv.w);
  *(float4*)(hout + (size_t)row * EMB + c) = o;
}

// ------------------------------------------------------------------ host ---
extern "C" void kernel_launch(void* const* d_in, const int* in_sizes, int n_in,
                              void* d_out, int out_size, void* d_ws, size_t ws_size,
                              hipStream_t stream) {
  const int* x    = (const int*)d_in[0];
  const int* ei   = (const int*)d_in[1];
  const int* ea   = (const int*)d_in[2];
  const float* xe1 = (const float*)d_in[3];
  const float* xe2 = (const float*)d_in[4];
  const float* ee1 = (const float*)d_in[5];
  const float* ee2 = (const float*)d_in[6];
  const float* W1  = (const float*)d_in[7];   // [L][256][512]
  const float* b1  = (const float*)d_in[8];   // [L][512]
  const float* W2  = (const float*)d_in[9];   // [L][512][256]
  const float* b2  = (const float*)d_in[10];  // [L][256]
  const float* bng = (const float*)d_in[11];
  const float* bnb = (const float*)d_in[12];

  char* ws = (char*)d_ws;
  size_t off = 0;
  ushort* aggh = (ushort*)(ws + off); off += (size_t)NNP * 256 * 2;
  ushort* hh2  = (ushort*)(ws + off); off += (size_t)NNP * 256 * 2;
  ushort* hid  = (ushort*)(ws + off); off += (size_t)NNP * 512 * 2;
  ushort* hh   = (ushort*)(ws + off); off += (size_t)NNP * 256 * 2;
  ushort* w1t  = (ushort*)(ws + off); off += (size_t)NL * 512 * 256 * 2;
  ushort* w2t  = (ushort*)(ws + off); off += (size_t)NL * 256 * 512 * 2;
  float* ecomb = (float*)(ws + off); off += (size_t)NL * 10 * EMB * 4;
  float* stats = (float*)(ws + off); off += 512 * 4;
  float* part_s = (float*)(ws + off); off += (size_t)NPART * 256 * 4;
  float* part_q = (float*)(ws + off); off += (size_t)NPART * 256 * 4;
  int* rowptr = (int*)(ws + off); off += (size_t)(NN + 1) * 4;
  int* cursor = (int*)(ws + off); off += (size_t)NN * 4;
  int* bsum = (int*)(ws + off); off += (size_t)(NBLK + 2) * 4;
  int* boff = (int*)(ws + off); off += (size_t)(NBLK + 2) * 4;
  int* ebuf   = (int*)(ws + off); off += (size_t)NE * 4;
  int* deg = ebuf;   // alias: deg dead before ebuf written

  // one-time prep
  hipMemsetAsync(deg, 0, NN * sizeof(int), stream);
  k_hist<<<(NE + 255) / 256, 256, 0, stream>>>(deg, ei);
  k_scan_a<<<NBLK, 256, 0, stream>>>(deg, bsum);
  k_scan_b<<<1, 128, 0, stream>>>(bsum, boff, rowptr);
  k_scan_c<<<NBLK, 256, 0, stream>>>(deg, boff, rowptr, cursor);
  k_bucket<<<(NE + 255) / 256, 256, 0, stream>>>(ebuf, cursor, ei, ea);
  k_sortseg<<<(NN + 255) / 256, 256, 0, stream>>>(ebuf, rowptr);
  k_ecomb<<<NL * 10, 256, 0, stream>>>(ecomb, ee1, ee2);
  for (int l = 0; l < NL; ++l) {
    k_wt<<<dim3(512 / 32, 256 / 32), 256, 0, stream>>>(
        W1 + (size_t)l * 256 * 512, w1t + (size_t)l * 512 * 256, 256, 512);
    k_wt<<<dim3(256 / 32, 512 / 32), 256, 0, stream>>>(
        W2 + (size_t)l * 512 * 256, w2t + (size_t)l * 256 * 512, 512, 256);
  }
  k_embed<<<NN / 4, 256, 0, stream>>>(hh, x, xe1, xe2);

  for (int l = 0; l < NL; ++l) {
    k_gather<<<NN / 4, 256, 0, stream>>>(
        aggh, l == 0 ? hh : hh2, rowptr, ebuf,
        ecomb + (size_t)l * 10 * EMB, stats, l == 0 ? 0 : 1);
    k_mfma1<<<dim3(4, NNP / 128), 256, 0, stream>>>(
        aggh, w1t + (size_t)l * 512 * 256, b1 + (size_t)l * 512, hid);
    k_mfma2<<<dim3(2, NNP / 128), 256, 0, stream>>>(
        hid, w2t + (size_t)l * 256 * 512, b2 + (size_t)l * 256, hh2,
        part_s, part_q);
    k_bnfin<<<256, 128, 0, stream>>>(stats, part_s, part_q,
                                     bng + (size_t)l * EMB, bnb + (size_t)l * EMB);
  }
  k_bnapply<<<NN / 4, 256, 0, stream>>>(hh2, stats, (float*)d_out);
}